// Round 6
// baseline (387.282 us; speedup 1.0000x reference)
//
#include <hip/hip_runtime.h>

#define NN 100000
#define NE 1600000
#define NG 4096
#define HD 128
#define EPSV 1e-5f
#define NBUCK 782            // ceil(NN/128), 128-node buckets
#define BIN_CHUNK 2048
#define NBIN_BLK ((NE + BIN_CHUNK - 1) / BIN_CHUNK)   // 782
#define CSR_CAP 4352
#define NB_AG 4096           // agg stats blocks
#define CH_AG 25             // ceil(NN/NB_AG)
#define NB_MM 2048           // mm9 stats blocks
#define CH_MM 49             // ceil(NN/NB_MM)

typedef _Float16 half_t;
typedef _Float16 half8 __attribute__((ext_vector_type(8)));
typedef _Float16 half4v __attribute__((ext_vector_type(4)));
typedef _Float16 half2v __attribute__((ext_vector_type(2)));
typedef float f32x4 __attribute__((ext_vector_type(4)));

// ---------------- bucketed CSR build ----------------

__global__ void k_zero_i32(int* p, int n) {
    int i = blockIdx.x * blockDim.x + threadIdx.x;
    if (i < n) p[i] = 0;
}

__global__ void k_bcount(const int* __restrict__ ei, int* __restrict__ bcnt) {
    __shared__ int cnt[NBUCK];
    int t = threadIdx.x;
    for (int i = t; i < NBUCK; i += 256) cnt[i] = 0;
    __syncthreads();
    int e0 = blockIdx.x * BIN_CHUNK;
    int e1 = min(NE, e0 + BIN_CHUNK);
    for (int e = e0 + t; e < e1; e += 256)
        atomicAdd(&cnt[ei[NE + e] >> 7], 1);
    __syncthreads();
    for (int i = t; i < NBUCK; i += 256)
        if (cnt[i]) atomicAdd(&bcnt[i], cnt[i]);
}

__global__ __launch_bounds__(1024) void k_bscan(const int* __restrict__ bcnt,
        int* __restrict__ ebase, int* __restrict__ gcur) {
    __shared__ int s[1024];
    int t = threadIdx.x;
    int v = (t < NBUCK) ? bcnt[t] : 0;
    s[t] = v;
    __syncthreads();
    for (int off = 1; off < 1024; off <<= 1) {
        int x = (t >= off) ? s[t - off] : 0;
        __syncthreads();
        s[t] += x;
        __syncthreads();
    }
    if (t <= NBUCK) {
        int ex = s[t] - v;
        ebase[t] = ex;
        if (t < NBUCK) gcur[t] = ex;
    }
}

__global__ void k_bin(const int* __restrict__ ei, int* __restrict__ gcur, unsigned* __restrict__ binned) {
    __shared__ int cnt[NBUCK];
    __shared__ int cur[NBUCK];
    int t = threadIdx.x;
    for (int i = t; i < NBUCK; i += 256) cnt[i] = 0;
    __syncthreads();
    int e0 = blockIdx.x * BIN_CHUNK;
    int e1 = min(NE, e0 + BIN_CHUNK);
    for (int e = e0 + t; e < e1; e += 256)
        atomicAdd(&cnt[ei[NE + e] >> 7], 1);
    __syncthreads();
    for (int i = t; i < NBUCK; i += 256)
        cur[i] = cnt[i] ? atomicAdd(&gcur[i], cnt[i]) : 0;
    __syncthreads();
    for (int e = e0 + t; e < e1; e += 256) {
        int d = ei[NE + e];
        int b = d >> 7;
        int r = atomicAdd(&cur[b], 1);
        binned[r] = ((unsigned)ei[e] << 7) | (unsigned)(d & 127);
    }
}

// one block per 128-node bucket
__global__ __launch_bounds__(256) void k_csr(const unsigned* __restrict__ binned,
        const int* __restrict__ ebase, int* __restrict__ rp,
        float* __restrict__ dinv, int* __restrict__ col) {
    __shared__ int colb[CSR_CAP];
    __shared__ int deg[128], cur[128], s[128];
    int b = blockIdx.x, t = threadIdx.x;
    int n0 = b * 128;
    int nodes = min(128, NN - n0);
    int cbeg = ebase[b];
    int cnt_b = min(ebase[b + 1] - cbeg, CSR_CAP - 128);
    int base = cbeg + n0;        // self-loops of earlier buckets = n0
    if (t < 128) deg[t] = 0;
    __syncthreads();
    for (int i = t; i < cnt_b; i += 256)
        atomicAdd(&deg[binned[cbeg + i] & 127], 1);
    __syncthreads();
    if (t < 128) s[t] = (t < nodes) ? deg[t] + 1 : 0;
    __syncthreads();
    for (int o = 1; o < 128; o <<= 1) {
        int x = 0;
        if (t < 128 && t >= o) x = s[t - o];
        __syncthreads();
        if (t < 128) s[t] += x;
        __syncthreads();
    }
    if (t < 128) {
        int w = (t < nodes) ? deg[t] + 1 : 0;
        int ex = s[t] - w;
        cur[t] = ex;
        if (t < nodes) {
            rp[n0 + t] = base + ex;
            dinv[n0 + t] = rsqrtf((float)(deg[t] + 1));
        }
    }
    __syncthreads();
    for (int i = t; i < cnt_b; i += 256) {
        unsigned pk = binned[cbeg + i];
        int d = pk & 127;
        int r = atomicAdd(&cur[d], 1);
        colb[r] = (int)(pk >> 7);
    }
    __syncthreads();
    if (t < nodes) colb[cur[t]] = n0 + t;    // self-loop at end of row
    __syncthreads();
    int tot = cnt_b + nodes;
    for (int i = t; i < tot; i += 256) col[base + i] = colb[i];
    if (b == 0 && t == 0) rp[NN] = NE + NN;
}

// ---------------- weight prep: Wt[m][n][k] = w12[m][k][n] as fp16 ----------------

__global__ void k_cvtw(const float* __restrict__ w12, half_t* __restrict__ Wt) {
    int i = blockIdx.x * 256 + threadIdx.x;   // 32768
    int m = i >> 14;
    int r = i & 16383;
    int n = r >> 7, k = r & 127;
    Wt[i] = (half_t)w12[m * 16384 + k * 128 + n];
}

// ---------------- layer 0 ----------------

__global__ void k_padx(const float* __restrict__ x, const float* __restrict__ dinv,
                       half_t* __restrict__ xh) {
    int n = blockIdx.x * 256 + threadIdx.x;
    if (n >= NN) return;
    float dv = dinv[n];
    half_t buf[16];
#pragma unroll
    for (int k = 0; k < 9; ++k) buf[k] = (half_t)(x[n * 9 + k] * dv);
#pragma unroll
    for (int k = 9; k < 16; ++k) buf[k] = (half_t)0.f;
    *(half8*)&xh[n * 16] = *(half8*)buf;
    *(half8*)&xh[n * 16 + 8] = *(half8*)(buf + 8);
}

// 4 lanes per node, half4 (8B) per lane
__global__ void k_aggx(const half_t* __restrict__ xh, const float* __restrict__ dinv,
                       float* __restrict__ aggx,
                       const int* __restrict__ rp, const int* __restrict__ col) {
    int t = blockIdx.x * blockDim.x + threadIdx.x;
    int n = t >> 2, sub = (t & 3) * 4;
    if (n >= NN) return;
    int s = rp[n], e = rp[n + 1];
    float acc[4] = {0.f, 0.f, 0.f, 0.f};
    int i = s;
    for (; i + 1 < e; i += 2) {
        half4v v0 = *(const half4v*)&xh[col[i] * 16 + sub];
        half4v v1 = *(const half4v*)&xh[col[i + 1] * 16 + sub];
#pragma unroll
        for (int j = 0; j < 4; ++j) acc[j] += (float)v0[j] + (float)v1[j];
    }
    if (i < e) {
        half4v v0 = *(const half4v*)&xh[col[i] * 16 + sub];
#pragma unroll
        for (int j = 0; j < 4; ++j) acc[j] += (float)v0[j];
    }
    float dv = dinv[n];
    f32x4 o = {acc[0] * dv, acc[1] * dv, acc[2] * dv, acc[3] * dv};
    *(f32x4*)&aggx[n * 16 + sub] = o;
}

// aggx [N,16(9)] @ w0 [9,128] -> gf fp16 + fused stats partials
__global__ __launch_bounds__(256) void k_mm9(const float* __restrict__ aggx,
        const float* __restrict__ w0, half_t* __restrict__ gout,
        float* __restrict__ ps, float* __restrict__ ps2) {
    __shared__ float lsum[4][128], lsq[4][128];
    int t = threadIdx.x, w = t >> 6, l = t & 63;
    int c = 2 * l;
    int n0 = blockIdx.x * CH_MM;
    int n1 = min(NN, n0 + CH_MM);
    float s0 = 0.f, s1 = 0.f, q0 = 0.f, q1 = 0.f;
    for (int n = n0 + w; n < n1; n += 4) {
        float2 acc = make_float2(0.f, 0.f);
#pragma unroll
        for (int k = 0; k < 9; ++k) {
            float a = aggx[n * 16 + k];
            float2 wv = *(const float2*)&w0[k * HD + c];
            acc.x += a * wv.x;
            acc.y += a * wv.y;
        }
        half_t hx = (half_t)acc.x, hy = (half_t)acc.y;
        half2v hv = {hx, hy};
        *(half2v*)&gout[n * HD + c] = hv;
        float fx = (float)hx, fy = (float)hy;
        s0 += fx; q0 += fx * fx; s1 += fy; q1 += fy * fy;
    }
    lsum[w][c] = s0; lsum[w][c + 1] = s1;
    lsq[w][c] = q0;  lsq[w][c + 1] = q1;
    __syncthreads();
    if (t < 128) {
        ps[blockIdx.x * 128 + t] = lsum[0][t] + lsum[1][t] + lsum[2][t] + lsum[3][t];
        ps2[blockIdx.x * 128 + t] = lsq[0][t] + lsq[1][t] + lsq[2][t] + lsq[3][t];
    }
}

// one block per channel, tree-reduce nb partials
__global__ __launch_bounds__(256) void k_stats2(const float* __restrict__ ps,
        const float* __restrict__ ps2, const float* __restrict__ g,
        const float* __restrict__ be, float* __restrict__ scale,
        float* __restrict__ shift, int nb) {
    __shared__ float sa[256], sb[256];
    int c = blockIdx.x, t = threadIdx.x;
    float S = 0.f, Q = 0.f;
    for (int i = t; i < nb; i += 256) {
        S += ps[i * 128 + c];
        Q += ps2[i * 128 + c];
    }
    sa[t] = S; sb[t] = Q;
    __syncthreads();
    for (int o = 128; o; o >>= 1) {
        if (t < o) { sa[t] += sa[t + o]; sb[t] += sb[t + o]; }
        __syncthreads();
    }
    if (t == 0) {
        double mu = (double)sa[0] / NN;
        double var = (double)sb[0] / NN - mu * mu;
        float sc = g[c] * rsqrtf((float)var + EPSV);
        scale[c] = sc;
        shift[c] = be[c] - (float)mu * sc;
    }
}

// ---------------- MFMA matmul: hh = relu(bn(gf)) @ W · dinv, fp16 out ----------------

__global__ __launch_bounds__(256) void k_mm_mfma(const half_t* __restrict__ gf,
        const float* __restrict__ scale, const float* __restrict__ shift,
        const float* __restrict__ dinv, const half_t* __restrict__ Wt,
        half_t* __restrict__ hh) {
    __shared__ half_t wlds[16384];   // [n][k] fp16, 16B-XOR swizzled
    int t = threadIdx.x;
#pragma unroll
    for (int j = 0; j < 8; ++j) {
        int cidx = t * 8 + j;          // 16-B chunk
        int n = cidx >> 4, k8 = cidx & 15;
        half8 v = *(const half8*)&Wt[cidx * 8];
        int byte = n * 256 + ((k8 * 16) ^ ((n & 7) << 4));
        *(half8*)((char*)wlds + byte) = v;
    }
    __syncthreads();
    int w = t >> 6, l = t & 63;
    int lr = l & 15, lg = l >> 4;
    int base = (blockIdx.x * 4 + w) * 16;
    int row = base + lr;
    bool rowok = row < NN;
    f32x4 acc[8];
#pragma unroll
    for (int nt = 0; nt < 8; ++nt) acc[nt] = (f32x4){0.f, 0.f, 0.f, 0.f};
#pragma unroll
    for (int kk = 0; kk < 4; ++kk) {
        int ch0 = kk * 32 + lg * 8;
        half8 a8;
        if (rowok) {
            half8 hv = *(const half8*)&gf[row * HD + ch0];
            f32x4 sc0 = *(const f32x4*)&scale[ch0];
            f32x4 sc1 = *(const f32x4*)&scale[ch0 + 4];
            f32x4 sh0 = *(const f32x4*)&shift[ch0];
            f32x4 sh1 = *(const f32x4*)&shift[ch0 + 4];
#pragma unroll
            for (int i = 0; i < 4; ++i)
                a8[i] = (half_t)fmaxf((float)hv[i] * sc0[i] + sh0[i], 0.f);
#pragma unroll
            for (int i = 0; i < 4; ++i)
                a8[4 + i] = (half_t)fmaxf((float)hv[4 + i] * sc1[i] + sh1[i], 0.f);
        } else {
#pragma unroll
            for (int i = 0; i < 8; ++i) a8[i] = (half_t)0.f;
        }
        int kbyte = kk * 64 + lg * 16;
#pragma unroll
        for (int nt = 0; nt < 8; ++nt) {
            int n = nt * 16 + lr;
            half8 b8 = *(const half8*)((const char*)wlds + n * 256 + (kbyte ^ ((n & 7) << 4)));
            acc[nt] = __builtin_amdgcn_mfma_f32_16x16x32_f16(a8, b8, acc[nt], 0, 0, 0);
        }
    }
#pragma unroll
    for (int i = 0; i < 4; ++i) {
        int r = base + lg * 4 + i;
        if (r < NN) {
            float dv = dinv[r];
#pragma unroll
            for (int nt = 0; nt < 8; ++nt)
                hh[r * HD + nt * 16 + lr] = (half_t)(acc[nt][i] * dv);
        }
    }
}

// ---------------- fp16 CSR gather (16-lane sub-groups, 4-unrolled) + fused stats ----------------

__global__ __launch_bounds__(256) void k_agg_h(const half_t* __restrict__ hh,
        const float* __restrict__ dinv, half_t* __restrict__ gout,
        const int* __restrict__ rp, const int* __restrict__ col,
        float* __restrict__ ps, float* __restrict__ ps2) {
    __shared__ float lsum[16][128], lsq[16][128];
    int t = threadIdx.x, w = t >> 6, l = t & 63;
    int sub = l >> 4, li = l & 15;
    int sg = w * 4 + sub;             // 0..15
    int c0 = li * 8;
    int n0 = blockIdx.x * CH_AG;
    int n1 = min(NN, n0 + CH_AG);
    float sacc[8], qacc[8];
#pragma unroll
    for (int j = 0; j < 8; ++j) { sacc[j] = 0.f; qacc[j] = 0.f; }
    for (int n = n0 + sg; n < n1; n += 16) {
        int s = rp[n], e = rp[n + 1];
        float facc[8];
#pragma unroll
        for (int j = 0; j < 8; ++j) facc[j] = 0.f;
        int i = s;
        for (; i + 3 < e; i += 4) {
            int ca = col[i], cb = col[i + 1], cc = col[i + 2], cd = col[i + 3];
            half8 v0 = *(const half8*)&hh[ca * HD + c0];
            half8 v1 = *(const half8*)&hh[cb * HD + c0];
            half8 v2 = *(const half8*)&hh[cc * HD + c0];
            half8 v3 = *(const half8*)&hh[cd * HD + c0];
#pragma unroll
            for (int j = 0; j < 8; ++j)
                facc[j] += ((float)v0[j] + (float)v1[j]) + ((float)v2[j] + (float)v3[j]);
        }
        for (; i + 1 < e; i += 2) {
            int ca = col[i], cb = col[i + 1];
            half8 v0 = *(const half8*)&hh[ca * HD + c0];
            half8 v1 = *(const half8*)&hh[cb * HD + c0];
#pragma unroll
            for (int j = 0; j < 8; ++j) facc[j] += (float)v0[j] + (float)v1[j];
        }
        if (i < e) {
            half8 v0 = *(const half8*)&hh[col[i] * HD + c0];
#pragma unroll
            for (int j = 0; j < 8; ++j) facc[j] += (float)v0[j];
        }
        float dv = dinv[n];
        half8 hv;
#pragma unroll
        for (int j = 0; j < 8; ++j) hv[j] = (half_t)(facc[j] * dv);
        *(half8*)&gout[n * HD + c0] = hv;
#pragma unroll
        for (int j = 0; j < 8; ++j) {
            float f = (float)hv[j];
            sacc[j] += f;
            qacc[j] += f * f;
        }
    }
#pragma unroll
    for (int j = 0; j < 8; ++j) {
        lsum[sg][c0 + j] = sacc[j];
        lsq[sg][c0 + j] = qacc[j];
    }
    __syncthreads();
    if (t < 128) {
        float S = 0.f, Q = 0.f;
#pragma unroll
        for (int g = 0; g < 16; ++g) { S += lsum[g][t]; Q += lsq[g][t]; }
        ps[blockIdx.x * 128 + t] = S;
        ps2[blockIdx.x * 128 + t] = Q;
    }
}

// ---------------- pooling (fused final BN+ReLU) + MLP ----------------

__global__ void k_pool_fused(const half_t* __restrict__ h, const float* __restrict__ scale,
                             const float* __restrict__ shift, const int* __restrict__ batch,
                             float* __restrict__ xg) {
    int l = threadIdx.x & 63;
    int g = blockIdx.x * (blockDim.x >> 6) + (threadIdx.x >> 6);
    if (g >= NG) return;
    int c = 2 * l;
    float2 sc = make_float2(scale[c], scale[c + 1]);
    float2 sh = make_float2(shift[c], shift[c + 1]);
    int lo = 0, hi = NN;
    while (lo < hi) { int m = (lo + hi) >> 1; if (batch[m] < g) lo = m + 1; else hi = m; }
    int s = lo;
    hi = NN;
    while (lo < hi) { int m = (lo + hi) >> 1; if (batch[m] < g + 1) lo = m + 1; else hi = m; }
    int e = lo;
    float2 sum = make_float2(0.f, 0.f), mx = make_float2(-3e38f, -3e38f);
    for (int r = s; r < e; ++r) {
        half2v hv = *(const half2v*)&h[r * HD + c];
        float vx = fmaxf((float)hv[0] * sc.x + sh.x, 0.f);
        float vy = fmaxf((float)hv[1] * sc.y + sh.y, 0.f);
        sum.x += vx; sum.y += vy;
        mx.x = fmaxf(mx.x, vx); mx.y = fmaxf(mx.y, vy);
    }
    float2 mean = make_float2(0.f, 0.f), mxo = make_float2(0.f, 0.f);
    if (e > s) {
        float cnt = (float)(e - s);
        mean.x = sum.x / cnt; mean.y = sum.y / cnt;
        mxo = mx;
    }
    *(float2*)&xg[g * 256 + c] = mean;
    *(float2*)&xg[g * 256 + 128 + c] = mxo;
}

#define GPB 8
__global__ __launch_bounds__(256) void k_mlp(const float* __restrict__ xg,
                                             const float* __restrict__ m0w, const float* __restrict__ m0b,
                                             const float* __restrict__ m1w, const float* __restrict__ m1b,
                                             const float* __restrict__ m2w, const float* __restrict__ m2b,
                                             float* __restrict__ out) {
    __shared__ float xs[GPB][256];
    __shared__ float h1[GPB][256];
    __shared__ float h2[GPB][64];
    int t = threadIdx.x;
    int g0 = blockIdx.x * GPB;
#pragma unroll
    for (int j = 0; j < GPB; ++j) xs[j][t] = xg[(g0 + j) * 256 + t];
    __syncthreads();
    float acc[GPB];
#pragma unroll
    for (int j = 0; j < GPB; ++j) acc[j] = m0b[t];
    for (int i = 0; i < 256; ++i) {
        float wv = m0w[i * 256 + t];
#pragma unroll
        for (int j = 0; j < GPB; ++j) acc[j] += xs[j][i] * wv;
    }
#pragma unroll
    for (int j = 0; j < GPB; ++j) h1[j][t] = fmaxf(acc[j], 0.f);
    __syncthreads();
    if (t < 64) {
        float a2[GPB];
#pragma unroll
        for (int j = 0; j < GPB; ++j) a2[j] = m1b[t];
        for (int i = 0; i < 256; ++i) {
            float wv = m1w[i * 64 + t];
#pragma unroll
            for (int j = 0; j < GPB; ++j) a2[j] += h1[j][i] * wv;
        }
#pragma unroll
        for (int j = 0; j < GPB; ++j) h2[j][t] = fmaxf(a2[j], 0.f);
    }
    __syncthreads();
    if (t < 64) {
#pragma unroll
        for (int j = 0; j < GPB; ++j) {
            float v = h2[j][t] * m2w[t];
            for (int off = 32; off; off >>= 1) v += __shfl_down(v, off);
            if (t == 0) out[g0 + j] = v + m2b[0];
        }
    }
}

// ---------------- launch ----------------

extern "C" void kernel_launch(void* const* d_in, const int* in_sizes, int n_in,
                              void* d_out, int out_size, void* d_ws, size_t ws_size,
                              hipStream_t stream) {
    const float* x    = (const float*)d_in[0];
    const int*   ei   = (const int*)d_in[1];
    const int*   batch= (const int*)d_in[2];
    const float* w0   = (const float*)d_in[3];
    const float* w12  = (const float*)d_in[4];
    // d_in[5] = cb : cancelled by BN mean-subtraction
    const float* bn_g = (const float*)d_in[6];
    const float* bn_b = (const float*)d_in[7];
    const float* m0w  = (const float*)d_in[8];
    const float* m0b  = (const float*)d_in[9];
    const float* m1w  = (const float*)d_in[10];
    const float* m1b  = (const float*)d_in[11];
    const float* m2w  = (const float*)d_in[12];
    const float* m2b  = (const float*)d_in[13];
    float* out = (float*)d_out;

    char* p = (char*)d_ws;
    auto alloc = [&](size_t bytes) {
        void* r = (void*)p;
        p += (bytes + 255) & ~(size_t)255;
        return r;
    };
    half_t*   gf0    = (half_t*)alloc((size_t)NN * HD * 2);
    half_t*   gf1    = (half_t*)alloc((size_t)NN * HD * 2);
    half_t*   hh     = (half_t*)alloc((size_t)NN * HD * 2);
    half_t*   xh     = (half_t*)alloc((size_t)NN * 16 * 2);
    float*    aggx   = (float*)alloc((size_t)NN * 16 * 4);
    half_t*   Wt     = (half_t*)alloc((size_t)2 * 128 * 128 * 2);
    float*    dinv   = (float*)alloc((size_t)NN * 4);
    int*      rp     = (int*)alloc((size_t)(NN + 1) * 4);
    int*      col    = (int*)alloc((size_t)(NE + NN) * 4);
    unsigned* binned = (unsigned*)alloc((size_t)NE * 4);
    int*      bcnt   = (int*)alloc(1024 * 4);
    int*      ebase  = (int*)alloc(1024 * 4);
    int*      gcur   = (int*)alloc(1024 * 4);
    float*    ps     = (float*)alloc((size_t)NB_AG * 128 * 4);
    float*    ps2    = (float*)alloc((size_t)NB_AG * 128 * 4);
    float*    scb    = (float*)alloc(3 * 128 * 4);
    float*    shb    = (float*)alloc(3 * 128 * 4);
    float*    xg     = (float*)alloc((size_t)NG * 256 * 4);

    // ---- CSR build ----
    k_zero_i32<<<4, 256, 0, stream>>>(bcnt, 1024);
    k_bcount<<<NBIN_BLK, 256, 0, stream>>>(ei, bcnt);
    k_bscan<<<1, 1024, 0, stream>>>(bcnt, ebase, gcur);
    k_bin<<<NBIN_BLK, 256, 0, stream>>>(ei, gcur, binned);
    k_csr<<<NBUCK, 256, 0, stream>>>(binned, ebase, rp, dinv, col);

    // ---- weight prep ----
    k_cvtw<<<128, 256, 0, stream>>>(w12, Wt);

    // ---- layer 0 ----
    k_padx<<<(NN + 255) / 256, 256, 0, stream>>>(x, dinv, xh);
    k_aggx<<<(NN * 4 + 255) / 256, 256, 0, stream>>>(xh, dinv, aggx, rp, col);
    k_mm9<<<NB_MM, 256, 0, stream>>>(aggx, w0, gf0, ps, ps2);
    k_stats2<<<128, 256, 0, stream>>>(ps, ps2, bn_g + 0, bn_b + 0, scb + 0, shb + 0, NB_MM);

    // ---- layer 1 ----
    k_mm_mfma<<<(NN + 63) / 64, 256, 0, stream>>>(gf0, scb + 0, shb + 0, dinv, Wt, hh);
    k_agg_h<<<NB_AG, 256, 0, stream>>>(hh, dinv, gf1, rp, col, ps, ps2);
    k_stats2<<<128, 256, 0, stream>>>(ps, ps2, bn_g + 128, bn_b + 128, scb + 128, shb + 128, NB_AG);

    // ---- layer 2 ----
    k_mm_mfma<<<(NN + 63) / 64, 256, 0, stream>>>(gf1, scb + 128, shb + 128, dinv, Wt + 16384, hh);
    k_agg_h<<<NB_AG, 256, 0, stream>>>(hh, dinv, gf0, rp, col, ps, ps2);
    k_stats2<<<128, 256, 0, stream>>>(ps, ps2, bn_g + 256, bn_b + 256, scb + 256, shb + 256, NB_AG);

    // ---- pool + MLP ----
    k_pool_fused<<<NG / 4, 256, 0, stream>>>(gf0, scb + 256, shb + 256, batch, xg);
    k_mlp<<<NG / GPB, 256, 0, stream>>>(xg, m0w, m0b, m1w, m1b, m2w, m2b, out);
}

// Round 7
// 384.036 us; speedup vs baseline: 1.0085x; 1.0085x over previous
//
#include <hip/hip_runtime.h>

#define NN 100000
#define NE 1600000
#define NG 4096
#define HD 128
#define EPSV 1e-5f
#define NBUCK 391            // ceil(NN/256)
#define BIN_CHUNK 4096
#define NBIN_BLK ((NE + BIN_CHUNK - 1) / BIN_CHUNK)   // 391
#define CSR_CAP 8448
#define NB_AG 6250           // agg blocks: 16 nodes each -> 1 node per subgroup
#define CH_AG 16
#define NB_MM 2048           // mm9 stats blocks
#define CH_MM 49             // ceil(NN/NB_MM)

typedef _Float16 half_t;
typedef _Float16 half8 __attribute__((ext_vector_type(8)));
typedef _Float16 half4v __attribute__((ext_vector_type(4)));
typedef _Float16 half2v __attribute__((ext_vector_type(2)));
typedef float f32x4 __attribute__((ext_vector_type(4)));

// ---------------- bucketed CSR build ----------------

__global__ void k_zero_i32(int* p, int n) {
    int i = blockIdx.x * blockDim.x + threadIdx.x;
    if (i < n) p[i] = 0;
}

__global__ void k_bcount(const int* __restrict__ ei, int* __restrict__ bcnt) {
    __shared__ int cnt[NBUCK];
    int t = threadIdx.x;
    for (int i = t; i < NBUCK; i += 256) cnt[i] = 0;
    __syncthreads();
    int e0 = blockIdx.x * BIN_CHUNK;
    int e1 = min(NE, e0 + BIN_CHUNK);
    for (int e = e0 + t; e < e1; e += 256)
        atomicAdd(&cnt[ei[NE + e] >> 8], 1);
    __syncthreads();
    for (int i = t; i < NBUCK; i += 256)
        if (cnt[i]) atomicAdd(&bcnt[i], cnt[i]);
}

__global__ void k_bscan(const int* __restrict__ bcnt, int* __restrict__ ebase, int* __restrict__ gcur) {
    __shared__ int s[512];
    int t = threadIdx.x;
    int v = (t < NBUCK) ? bcnt[t] : 0;
    s[t] = v;
    __syncthreads();
    for (int off = 1; off < 512; off <<= 1) {
        int x = (t >= off) ? s[t - off] : 0;
        __syncthreads();
        s[t] += x;
        __syncthreads();
    }
    if (t <= NBUCK) {
        int ex = s[t] - v;
        ebase[t] = ex;
        if (t < NBUCK) gcur[t] = ex;
    }
}

__global__ void k_bin(const int* __restrict__ ei, int* __restrict__ gcur, unsigned* __restrict__ binned) {
    __shared__ int cnt[NBUCK];
    __shared__ int cur[NBUCK];
    int t = threadIdx.x;
    for (int i = t; i < NBUCK; i += 256) cnt[i] = 0;
    __syncthreads();
    int e0 = blockIdx.x * BIN_CHUNK;
    int e1 = min(NE, e0 + BIN_CHUNK);
    for (int e = e0 + t; e < e1; e += 256)
        atomicAdd(&cnt[ei[NE + e] >> 8], 1);
    __syncthreads();
    for (int i = t; i < NBUCK; i += 256)
        cur[i] = cnt[i] ? atomicAdd(&gcur[i], cnt[i]) : 0;
    __syncthreads();
    for (int e = e0 + t; e < e1; e += 256) {
        int d = ei[NE + e];
        int b = d >> 8;
        int r = atomicAdd(&cur[b], 1);
        binned[r] = ((unsigned)ei[e] << 8) | (unsigned)(d & 255);
    }
}

__global__ __launch_bounds__(256) void k_csr(const unsigned* __restrict__ binned,
        const int* __restrict__ ebase, int* __restrict__ rp,
        float* __restrict__ dinv, int* __restrict__ col) {
    __shared__ int colb[CSR_CAP];
    __shared__ int deg[256], cur[256], s[256];
    int b = blockIdx.x, t = threadIdx.x;
    int n0 = b * 256;
    int nodes = min(256, NN - n0);
    int cbeg = ebase[b];
    int cnt_b = min(ebase[b + 1] - cbeg, CSR_CAP - 256);
    int base = cbeg + n0;
    deg[t] = 0;
    __syncthreads();
    for (int i = t; i < cnt_b; i += 256)
        atomicAdd(&deg[binned[cbeg + i] & 255], 1);
    __syncthreads();
    int w = (t < nodes) ? deg[t] + 1 : 0;
    s[t] = w;
    __syncthreads();
    for (int o = 1; o < 256; o <<= 1) {
        int x = (t >= o) ? s[t - o] : 0;
        __syncthreads();
        s[t] += x;
        __syncthreads();
    }
    int ex = s[t] - w;
    cur[t] = ex;
    if (t < nodes) {
        rp[n0 + t] = base + ex;
        dinv[n0 + t] = rsqrtf((float)(deg[t] + 1));
    }
    __syncthreads();
    for (int i = t; i < cnt_b; i += 256) {
        unsigned pk = binned[cbeg + i];
        int d = pk & 255;
        int r = atomicAdd(&cur[d], 1);
        colb[r] = (int)(pk >> 8);
    }
    __syncthreads();
    if (t < nodes) colb[cur[t]] = n0 + t;
    __syncthreads();
    int tot = cnt_b + nodes;
    for (int i = t; i < tot; i += 256) col[base + i] = colb[i];
    if (b == 0 && t == 0) rp[NN] = NE + NN;
}

// ---------------- fused prep: Wt transpose-cvt + x pad/scale ----------------

__global__ void k_prep(const float* __restrict__ w12, half_t* __restrict__ Wt,
                       const float* __restrict__ x, const float* __restrict__ dinv,
                       half_t* __restrict__ xh) {
    int b = blockIdx.x;
    if (b < 128) {           // cvtw: 128 blocks x 256 = 32768
        int i = b * 256 + threadIdx.x;
        int m = i >> 14;
        int r = i & 16383;
        int n = r >> 7, k = r & 127;
        Wt[i] = (half_t)w12[m * 16384 + k * 128 + n];
    } else {                 // padx
        int n = (b - 128) * 256 + threadIdx.x;
        if (n >= NN) return;
        float dv = dinv[n];
        half_t buf[16];
#pragma unroll
        for (int k = 0; k < 9; ++k) buf[k] = (half_t)(x[n * 9 + k] * dv);
#pragma unroll
        for (int k = 9; k < 16; ++k) buf[k] = (half_t)0.f;
        *(half8*)&xh[n * 16] = *(half8*)buf;
        *(half8*)&xh[n * 16 + 8] = *(half8*)(buf + 8);
    }
}

// ---------------- layer 0 ----------------

// 4 lanes per node, half4 (8B) per lane
__global__ void k_aggx(const half_t* __restrict__ xh, const float* __restrict__ dinv,
                       float* __restrict__ aggx,
                       const int* __restrict__ rp, const int* __restrict__ col) {
    int t = blockIdx.x * blockDim.x + threadIdx.x;
    int n = t >> 2, sub = (t & 3) * 4;
    if (n >= NN) return;
    int s = rp[n], e = rp[n + 1];
    float acc[4] = {0.f, 0.f, 0.f, 0.f};
    int i = s;
    for (; i + 1 < e; i += 2) {
        half4v v0 = *(const half4v*)&xh[col[i] * 16 + sub];
        half4v v1 = *(const half4v*)&xh[col[i + 1] * 16 + sub];
#pragma unroll
        for (int j = 0; j < 4; ++j) acc[j] += (float)v0[j] + (float)v1[j];
    }
    if (i < e) {
        half4v v0 = *(const half4v*)&xh[col[i] * 16 + sub];
#pragma unroll
        for (int j = 0; j < 4; ++j) acc[j] += (float)v0[j];
    }
    float dv = dinv[n];
    f32x4 o = {acc[0] * dv, acc[1] * dv, acc[2] * dv, acc[3] * dv};
    *(f32x4*)&aggx[n * 16 + sub] = o;
}

// aggx [N,16(9)] @ w0 [9,128] -> gf fp16 + fused stats partials
__global__ __launch_bounds__(256) void k_mm9(const float* __restrict__ aggx,
        const float* __restrict__ w0, half_t* __restrict__ gout,
        float* __restrict__ ps, float* __restrict__ ps2) {
    __shared__ float lsum[4][128], lsq[4][128];
    int t = threadIdx.x, w = t >> 6, l = t & 63;
    int c = 2 * l;
    int n0 = blockIdx.x * CH_MM;
    int n1 = min(NN, n0 + CH_MM);
    float s0 = 0.f, s1 = 0.f, q0 = 0.f, q1 = 0.f;
    for (int n = n0 + w; n < n1; n += 4) {
        float2 acc = make_float2(0.f, 0.f);
#pragma unroll
        for (int k = 0; k < 9; ++k) {
            float a = aggx[n * 16 + k];
            float2 wv = *(const float2*)&w0[k * HD + c];
            acc.x += a * wv.x;
            acc.y += a * wv.y;
        }
        half_t hx = (half_t)acc.x, hy = (half_t)acc.y;
        half2v hv = {hx, hy};
        *(half2v*)&gout[n * HD + c] = hv;
        float fx = (float)hx, fy = (float)hy;
        s0 += fx; q0 += fx * fx; s1 += fy; q1 += fy * fy;
    }
    lsum[w][c] = s0; lsum[w][c + 1] = s1;
    lsq[w][c] = q0;  lsq[w][c + 1] = q1;
    __syncthreads();
    if (t < 128) {
        ps[blockIdx.x * 128 + t] = lsum[0][t] + lsum[1][t] + lsum[2][t] + lsum[3][t];
        ps2[blockIdx.x * 128 + t] = lsq[0][t] + lsq[1][t] + lsq[2][t] + lsq[3][t];
    }
}

// one block per channel, tree-reduce nb partials
__global__ __launch_bounds__(256) void k_stats2(const float* __restrict__ ps,
        const float* __restrict__ ps2, const float* __restrict__ g,
        const float* __restrict__ be, float* __restrict__ scale,
        float* __restrict__ shift, int nb) {
    __shared__ float sa[256], sb[256];
    int c = blockIdx.x, t = threadIdx.x;
    float S = 0.f, Q = 0.f;
    for (int i = t; i < nb; i += 256) {
        S += ps[i * 128 + c];
        Q += ps2[i * 128 + c];
    }
    sa[t] = S; sb[t] = Q;
    __syncthreads();
    for (int o = 128; o; o >>= 1) {
        if (t < o) { sa[t] += sa[t + o]; sb[t] += sb[t + o]; }
        __syncthreads();
    }
    if (t == 0) {
        double mu = (double)sa[0] / NN;
        double var = (double)sb[0] / NN - mu * mu;
        float sc = g[c] * rsqrtf((float)var + EPSV);
        scale[c] = sc;
        shift[c] = be[c] - (float)mu * sc;
    }
}

// ---------------- MFMA matmul: hh = relu(bn(gf)) @ W · dinv, fp16 out ----------------

__global__ __launch_bounds__(256) void k_mm_mfma(const half_t* __restrict__ gf,
        const float* __restrict__ scale, const float* __restrict__ shift,
        const float* __restrict__ dinv, const half_t* __restrict__ Wt,
        half_t* __restrict__ hh) {
    __shared__ half_t wlds[16384];   // [n][k] fp16, 16B-XOR swizzled
    int t = threadIdx.x;
#pragma unroll
    for (int j = 0; j < 8; ++j) {
        int cidx = t * 8 + j;          // 16-B chunk
        int n = cidx >> 4, k8 = cidx & 15;
        half8 v = *(const half8*)&Wt[cidx * 8];
        int byte = n * 256 + ((k8 * 16) ^ ((n & 7) << 4));
        *(half8*)((char*)wlds + byte) = v;
    }
    __syncthreads();
    int w = t >> 6, l = t & 63;
    int lr = l & 15, lg = l >> 4;
    int base = (blockIdx.x * 4 + w) * 16;
    int row = base + lr;
    bool rowok = row < NN;
    f32x4 acc[8];
#pragma unroll
    for (int nt = 0; nt < 8; ++nt) acc[nt] = (f32x4){0.f, 0.f, 0.f, 0.f};
#pragma unroll
    for (int kk = 0; kk < 4; ++kk) {
        int ch0 = kk * 32 + lg * 8;
        half8 a8;
        if (rowok) {
            half8 hv = *(const half8*)&gf[row * HD + ch0];
            f32x4 sc0 = *(const f32x4*)&scale[ch0];
            f32x4 sc1 = *(const f32x4*)&scale[ch0 + 4];
            f32x4 sh0 = *(const f32x4*)&shift[ch0];
            f32x4 sh1 = *(const f32x4*)&shift[ch0 + 4];
#pragma unroll
            for (int i = 0; i < 4; ++i)
                a8[i] = (half_t)fmaxf((float)hv[i] * sc0[i] + sh0[i], 0.f);
#pragma unroll
            for (int i = 0; i < 4; ++i)
                a8[4 + i] = (half_t)fmaxf((float)hv[4 + i] * sc1[i] + sh1[i], 0.f);
        } else {
#pragma unroll
            for (int i = 0; i < 8; ++i) a8[i] = (half_t)0.f;
        }
        int kbyte = kk * 64 + lg * 16;
#pragma unroll
        for (int nt = 0; nt < 8; ++nt) {
            int n = nt * 16 + lr;
            half8 b8 = *(const half8*)((const char*)wlds + n * 256 + (kbyte ^ ((n & 7) << 4)));
            acc[nt] = __builtin_amdgcn_mfma_f32_16x16x32_f16(a8, b8, acc[nt], 0, 0, 0);
        }
    }
#pragma unroll
    for (int i = 0; i < 4; ++i) {
        int r = base + lg * 4 + i;
        if (r < NN) {
            float dv = dinv[r];
#pragma unroll
            for (int nt = 0; nt < 8; ++nt)
                hh[r * HD + nt * 16 + lr] = (half_t)(acc[nt][i] * dv);
        }
    }
}

// ---------------- fp16 CSR gather (16-lane sub-groups, 1 node each) + fused stats ----------------

__global__ __launch_bounds__(256) void k_agg_h(const half_t* __restrict__ hh,
        const float* __restrict__ dinv, half_t* __restrict__ gout,
        const int* __restrict__ rp, const int* __restrict__ col,
        float* __restrict__ ps, float* __restrict__ ps2) {
    __shared__ float lsum[4][128], lsq[4][128];
    int t = threadIdx.x, w = t >> 6, l = t & 63;
    int sub = l >> 4, li = l & 15;
    int sg = w * 4 + sub;             // 0..15
    int c0 = li * 8;
    int n = blockIdx.x * CH_AG + sg;  // exactly one node per sub-group
    float sacc[8], qacc[8];
#pragma unroll
    for (int j = 0; j < 8; ++j) { sacc[j] = 0.f; qacc[j] = 0.f; }
    if (n < NN) {
        int s = rp[n], e = rp[n + 1];
        float facc[8];
#pragma unroll
        for (int j = 0; j < 8; ++j) facc[j] = 0.f;
        int i = s;
        for (; i + 1 < e; i += 2) {
            int ca = col[i], cb = col[i + 1];
            half8 v0 = *(const half8*)&hh[ca * HD + c0];
            half8 v1 = *(const half8*)&hh[cb * HD + c0];
#pragma unroll
            for (int j = 0; j < 8; ++j) facc[j] += (float)v0[j] + (float)v1[j];
        }
        if (i < e) {
            half8 v0 = *(const half8*)&hh[col[i] * HD + c0];
#pragma unroll
            for (int j = 0; j < 8; ++j) facc[j] += (float)v0[j];
        }
        float dv = dinv[n];
        half8 hv;
#pragma unroll
        for (int j = 0; j < 8; ++j) hv[j] = (half_t)(facc[j] * dv);
        *(half8*)&gout[n * HD + c0] = hv;
#pragma unroll
        for (int j = 0; j < 8; ++j) {
            float f = (float)hv[j];
            sacc[j] = f;
            qacc[j] = f * f;
        }
    }
    // wave-combine the 4 sub-groups via shfl (lanes 0-15 end with wave totals)
#pragma unroll
    for (int j = 0; j < 8; ++j) {
        float s = sacc[j], q = qacc[j];
        s += __shfl_xor(s, 16); q += __shfl_xor(q, 16);
        s += __shfl_xor(s, 32); q += __shfl_xor(q, 32);
        sacc[j] = s; qacc[j] = q;
    }
    if (sub == 0) {
#pragma unroll
        for (int j = 0; j < 8; ++j) {
            lsum[w][c0 + j] = sacc[j];
            lsq[w][c0 + j] = qacc[j];
        }
    }
    __syncthreads();
    if (t < 128) {
        ps[blockIdx.x * 128 + t] = lsum[0][t] + lsum[1][t] + lsum[2][t] + lsum[3][t];
        ps2[blockIdx.x * 128 + t] = lsq[0][t] + lsq[1][t] + lsq[2][t] + lsq[3][t];
    }
}

// ---------------- pooling (fused final BN+ReLU) + MLP ----------------

__global__ void k_pool_fused(const half_t* __restrict__ h, const float* __restrict__ scale,
                             const float* __restrict__ shift, const int* __restrict__ batch,
                             float* __restrict__ xg) {
    int l = threadIdx.x & 63;
    int g = blockIdx.x * (blockDim.x >> 6) + (threadIdx.x >> 6);
    if (g >= NG) return;
    int c = 2 * l;
    float2 sc = make_float2(scale[c], scale[c + 1]);
    float2 sh = make_float2(shift[c], shift[c + 1]);
    int lo = 0, hi = NN;
    while (lo < hi) { int m = (lo + hi) >> 1; if (batch[m] < g) lo = m + 1; else hi = m; }
    int s = lo;
    hi = NN;
    while (lo < hi) { int m = (lo + hi) >> 1; if (batch[m] < g + 1) lo = m + 1; else hi = m; }
    int e = lo;
    float2 sum = make_float2(0.f, 0.f), mx = make_float2(-3e38f, -3e38f);
    for (int r = s; r < e; ++r) {
        half2v hv = *(const half2v*)&h[r * HD + c];
        float vx = fmaxf((float)hv[0] * sc.x + sh.x, 0.f);
        float vy = fmaxf((float)hv[1] * sc.y + sh.y, 0.f);
        sum.x += vx; sum.y += vy;
        mx.x = fmaxf(mx.x, vx); mx.y = fmaxf(mx.y, vy);
    }
    float2 mean = make_float2(0.f, 0.f), mxo = make_float2(0.f, 0.f);
    if (e > s) {
        float cnt = (float)(e - s);
        mean.x = sum.x / cnt; mean.y = sum.y / cnt;
        mxo = mx;
    }
    *(float2*)&xg[g * 256 + c] = mean;
    *(float2*)&xg[g * 256 + 128 + c] = mxo;
}

#define GPB 8
__global__ __launch_bounds__(256) void k_mlp(const float* __restrict__ xg,
                                             const float* __restrict__ m0w, const float* __restrict__ m0b,
                                             const float* __restrict__ m1w, const float* __restrict__ m1b,
                                             const float* __restrict__ m2w, const float* __restrict__ m2b,
                                             float* __restrict__ out) {
    __shared__ float xs[GPB][256];
    __shared__ float h1[GPB][256];
    __shared__ float h2[GPB][64];
    int t = threadIdx.x;
    int g0 = blockIdx.x * GPB;
#pragma unroll
    for (int j = 0; j < GPB; ++j) xs[j][t] = xg[(g0 + j) * 256 + t];
    __syncthreads();
    float acc[GPB];
#pragma unroll
    for (int j = 0; j < GPB; ++j) acc[j] = m0b[t];
    for (int i = 0; i < 256; ++i) {
        float wv = m0w[i * 256 + t];
#pragma unroll
        for (int j = 0; j < GPB; ++j) acc[j] += xs[j][i] * wv;
    }
#pragma unroll
    for (int j = 0; j < GPB; ++j) h1[j][t] = fmaxf(acc[j], 0.f);
    __syncthreads();
    if (t < 64) {
        float a2[GPB];
#pragma unroll
        for (int j = 0; j < GPB; ++j) a2[j] = m1b[t];
        for (int i = 0; i < 256; ++i) {
            float wv = m1w[i * 64 + t];
#pragma unroll
            for (int j = 0; j < GPB; ++j) a2[j] += h1[j][i] * wv;
        }
#pragma unroll
        for (int j = 0; j < GPB; ++j) h2[j][t] = fmaxf(a2[j], 0.f);
    }
    __syncthreads();
    if (t < 64) {
#pragma unroll
        for (int j = 0; j < GPB; ++j) {
            float v = h2[j][t] * m2w[t];
            for (int off = 32; off; off >>= 1) v += __shfl_down(v, off);
            if (t == 0) out[g0 + j] = v + m2b[0];
        }
    }
}

// ---------------- launch ----------------

extern "C" void kernel_launch(void* const* d_in, const int* in_sizes, int n_in,
                              void* d_out, int out_size, void* d_ws, size_t ws_size,
                              hipStream_t stream) {
    const float* x    = (const float*)d_in[0];
    const int*   ei   = (const int*)d_in[1];
    const int*   batch= (const int*)d_in[2];
    const float* w0   = (const float*)d_in[3];
    const float* w12  = (const float*)d_in[4];
    // d_in[5] = cb : cancelled by BN mean-subtraction
    const float* bn_g = (const float*)d_in[6];
    const float* bn_b = (const float*)d_in[7];
    const float* m0w  = (const float*)d_in[8];
    const float* m0b  = (const float*)d_in[9];
    const float* m1w  = (const float*)d_in[10];
    const float* m1b  = (const float*)d_in[11];
    const float* m2w  = (const float*)d_in[12];
    const float* m2b  = (const float*)d_in[13];
    float* out = (float*)d_out;

    char* p = (char*)d_ws;
    auto alloc = [&](size_t bytes) {
        void* r = (void*)p;
        p += (bytes + 255) & ~(size_t)255;
        return r;
    };
    half_t*   gf0    = (half_t*)alloc((size_t)NN * HD * 2);
    half_t*   gf1    = (half_t*)alloc((size_t)NN * HD * 2);
    half_t*   hh     = (half_t*)alloc((size_t)NN * HD * 2);
    half_t*   xh     = (half_t*)alloc((size_t)NN * 16 * 2);
    float*    aggx   = (float*)alloc((size_t)NN * 16 * 4);
    half_t*   Wt     = (half_t*)alloc((size_t)2 * 128 * 128 * 2);
    float*    dinv   = (float*)alloc((size_t)NN * 4);
    int*      rp     = (int*)alloc((size_t)(NN + 1) * 4);
    int*      col    = (int*)alloc((size_t)(NE + NN) * 4);
    unsigned* binned = (unsigned*)alloc((size_t)NE * 4);
    int*      bcnt   = (int*)alloc(512 * 4);
    int*      ebase  = (int*)alloc(512 * 4);
    int*      gcur   = (int*)alloc(512 * 4);
    float*    ps     = (float*)alloc((size_t)NB_AG * 128 * 4);
    float*    ps2    = (float*)alloc((size_t)NB_AG * 128 * 4);
    float*    scb    = (float*)alloc(3 * 128 * 4);
    float*    shb    = (float*)alloc(3 * 128 * 4);
    float*    xg     = (float*)alloc((size_t)NG * 256 * 4);

    // ---- CSR build ----
    k_zero_i32<<<2, 256, 0, stream>>>(bcnt, 512);
    k_bcount<<<NBIN_BLK, 256, 0, stream>>>(ei, bcnt);
    k_bscan<<<1, 512, 0, stream>>>(bcnt, ebase, gcur);
    k_bin<<<NBIN_BLK, 256, 0, stream>>>(ei, gcur, binned);
    k_csr<<<NBUCK, 256, 0, stream>>>(binned, ebase, rp, dinv, col);

    // ---- prep (Wt cvt + x pad) ----
    k_prep<<<128 + (NN + 255) / 256, 256, 0, stream>>>(w12, Wt, x, dinv, xh);

    // ---- layer 0 ----
    k_aggx<<<(NN * 4 + 255) / 256, 256, 0, stream>>>(xh, dinv, aggx, rp, col);
    k_mm9<<<NB_MM, 256, 0, stream>>>(aggx, w0, gf0, ps, ps2);
    k_stats2<<<128, 256, 0, stream>>>(ps, ps2, bn_g + 0, bn_b + 0, scb + 0, shb + 0, NB_MM);

    // ---- layer 1 ----
    k_mm_mfma<<<(NN + 63) / 64, 256, 0, stream>>>(gf0, scb + 0, shb + 0, dinv, Wt, hh);
    k_agg_h<<<NB_AG, 256, 0, stream>>>(hh, dinv, gf1, rp, col, ps, ps2);
    k_stats2<<<128, 256, 0, stream>>>(ps, ps2, bn_g + 128, bn_b + 128, scb + 128, shb + 128, NB_AG);

    // ---- layer 2 ----
    k_mm_mfma<<<(NN + 63) / 64, 256, 0, stream>>>(gf1, scb + 128, shb + 128, dinv, Wt + 16384, hh);
    k_agg_h<<<NB_AG, 256, 0, stream>>>(hh, dinv, gf0, rp, col, ps, ps2);
    k_stats2<<<128, 256, 0, stream>>>(ps, ps2, bn_g + 256, bn_b + 256, scb + 256, shb + 256, NB_AG);

    // ---- pool + MLP ----
    k_pool_fused<<<NG / 4, 256, 0, stream>>>(gf0, scb + 256, shb + 256, batch, xg);
    k_mlp<<<NG / GPB, 256, 0, stream>>>(xg, m0w, m0b, m1w, m1b, m2w, m2b, out);
}

// Round 8
// 371.484 us; speedup vs baseline: 1.0425x; 1.0338x over previous
//
#include <hip/hip_runtime.h>

#define NN 100000
#define NE 1600000
#define NG 4096
#define HD 128
#define EPSV 1e-5f
#define NBUCK 391            // ceil(NN/256)
#define BIN_CHUNK 4096
#define NBIN_BLK ((NE + BIN_CHUNK - 1) / BIN_CHUNK)   // 391
#define CSR_CAP 8448
#define NB_AG 4096           // agg stats blocks
#define CH_AG 25             // ceil(NN/NB_AG)
#define NB_MM 2048           // mm9 stats blocks
#define CH_MM 49             // ceil(NN/NB_MM)

typedef _Float16 half_t;
typedef _Float16 half8 __attribute__((ext_vector_type(8)));
typedef _Float16 half4v __attribute__((ext_vector_type(4)));
typedef _Float16 half2v __attribute__((ext_vector_type(2)));
typedef float f32x4 __attribute__((ext_vector_type(4)));

// ---------------- bucketed CSR build (round-5 exact) ----------------

__global__ void k_zero_i32(int* p, int n) {
    int i = blockIdx.x * blockDim.x + threadIdx.x;
    if (i < n) p[i] = 0;
}

__global__ void k_bcount(const int* __restrict__ ei, int* __restrict__ bcnt) {
    __shared__ int cnt[NBUCK];
    int t = threadIdx.x;
    for (int i = t; i < NBUCK; i += 256) cnt[i] = 0;
    __syncthreads();
    int e0 = blockIdx.x * BIN_CHUNK;
    int e1 = min(NE, e0 + BIN_CHUNK);
    for (int e = e0 + t; e < e1; e += 256)
        atomicAdd(&cnt[ei[NE + e] >> 8], 1);
    __syncthreads();
    for (int i = t; i < NBUCK; i += 256)
        if (cnt[i]) atomicAdd(&bcnt[i], cnt[i]);
}

__global__ void k_bscan(const int* __restrict__ bcnt, int* __restrict__ ebase, int* __restrict__ gcur) {
    __shared__ int s[512];
    int t = threadIdx.x;
    int v = (t < NBUCK) ? bcnt[t] : 0;
    s[t] = v;
    __syncthreads();
    for (int off = 1; off < 512; off <<= 1) {
        int x = (t >= off) ? s[t - off] : 0;
        __syncthreads();
        s[t] += x;
        __syncthreads();
    }
    if (t <= NBUCK) {
        int ex = s[t] - v;
        ebase[t] = ex;
        if (t < NBUCK) gcur[t] = ex;
    }
}

__global__ void k_bin(const int* __restrict__ ei, int* __restrict__ gcur, unsigned* __restrict__ binned) {
    __shared__ int cnt[NBUCK];
    __shared__ int cur[NBUCK];
    int t = threadIdx.x;
    for (int i = t; i < NBUCK; i += 256) cnt[i] = 0;
    __syncthreads();
    int e0 = blockIdx.x * BIN_CHUNK;
    int e1 = min(NE, e0 + BIN_CHUNK);
    for (int e = e0 + t; e < e1; e += 256)
        atomicAdd(&cnt[ei[NE + e] >> 8], 1);
    __syncthreads();
    for (int i = t; i < NBUCK; i += 256)
        cur[i] = cnt[i] ? atomicAdd(&gcur[i], cnt[i]) : 0;
    __syncthreads();
    for (int e = e0 + t; e < e1; e += 256) {
        int d = ei[NE + e];
        int b = d >> 8;
        int r = atomicAdd(&cur[b], 1);
        binned[r] = ((unsigned)ei[e] << 8) | (unsigned)(d & 255);
    }
}

__global__ __launch_bounds__(256) void k_csr(const unsigned* __restrict__ binned,
        const int* __restrict__ ebase, int* __restrict__ rp,
        float* __restrict__ dinv, int* __restrict__ col) {
    __shared__ int colb[CSR_CAP];
    __shared__ int deg[256], cur[256], s[256];
    int b = blockIdx.x, t = threadIdx.x;
    int n0 = b * 256;
    int nodes = min(256, NN - n0);
    int cbeg = ebase[b];
    int cnt_b = min(ebase[b + 1] - cbeg, CSR_CAP - 256);
    int base = cbeg + n0;
    deg[t] = 0;
    __syncthreads();
    for (int i = t; i < cnt_b; i += 256)
        atomicAdd(&deg[binned[cbeg + i] & 255], 1);
    __syncthreads();
    int w = (t < nodes) ? deg[t] + 1 : 0;
    s[t] = w;
    __syncthreads();
    for (int o = 1; o < 256; o <<= 1) {
        int x = (t >= o) ? s[t - o] : 0;
        __syncthreads();
        s[t] += x;
        __syncthreads();
    }
    int ex = s[t] - w;
    cur[t] = ex;
    if (t < nodes) {
        rp[n0 + t] = base + ex;
        dinv[n0 + t] = rsqrtf((float)(deg[t] + 1));
    }
    __syncthreads();
    for (int i = t; i < cnt_b; i += 256) {
        unsigned pk = binned[cbeg + i];
        int d = pk & 255;
        int r = atomicAdd(&cur[d], 1);
        colb[r] = (int)(pk >> 8);
    }
    __syncthreads();
    if (t < nodes) colb[cur[t]] = n0 + t;
    __syncthreads();
    int tot = cnt_b + nodes;
    for (int i = t; i < tot; i += 256) col[base + i] = colb[i];
    if (b == 0 && t == 0) rp[NN] = NE + NN;
}

// ---------------- fused prep: Wt transpose-cvt + x pad/scale ----------------

__global__ void k_prep(const float* __restrict__ w12, half_t* __restrict__ Wt,
                       const float* __restrict__ x, const float* __restrict__ dinv,
                       half_t* __restrict__ xh) {
    int b = blockIdx.x;
    if (b < 128) {           // cvtw: 128 blocks x 256 = 32768
        int i = b * 256 + threadIdx.x;
        int m = i >> 14;
        int r = i & 16383;
        int n = r >> 7, k = r & 127;
        Wt[i] = (half_t)w12[m * 16384 + k * 128 + n];
    } else {                 // padx
        int n = (b - 128) * 256 + threadIdx.x;
        if (n >= NN) return;
        float dv = dinv[n];
        half_t buf[16];
#pragma unroll
        for (int k = 0; k < 9; ++k) buf[k] = (half_t)(x[n * 9 + k] * dv);
#pragma unroll
        for (int k = 9; k < 16; ++k) buf[k] = (half_t)0.f;
        *(half8*)&xh[n * 16] = *(half8*)buf;
        *(half8*)&xh[n * 16 + 8] = *(half8*)(buf + 8);
    }
}

// ---------------- layer 0 ----------------

// 4 lanes per node, half4 (8B) per lane; fp16 out
__global__ void k_aggx(const half_t* __restrict__ xh, const float* __restrict__ dinv,
                       half_t* __restrict__ aggx,
                       const int* __restrict__ rp, const int* __restrict__ col) {
    int t = blockIdx.x * blockDim.x + threadIdx.x;
    int n = t >> 2, sub = (t & 3) * 4;
    if (n >= NN) return;
    int s = rp[n], e = rp[n + 1];
    float acc[4] = {0.f, 0.f, 0.f, 0.f};
    int i = s;
    for (; i + 1 < e; i += 2) {
        half4v v0 = *(const half4v*)&xh[col[i] * 16 + sub];
        half4v v1 = *(const half4v*)&xh[col[i + 1] * 16 + sub];
#pragma unroll
        for (int j = 0; j < 4; ++j) acc[j] += (float)v0[j] + (float)v1[j];
    }
    if (i < e) {
        half4v v0 = *(const half4v*)&xh[col[i] * 16 + sub];
#pragma unroll
        for (int j = 0; j < 4; ++j) acc[j] += (float)v0[j];
    }
    float dv = dinv[n];
    half4v o = {(half_t)(acc[0] * dv), (half_t)(acc[1] * dv),
                (half_t)(acc[2] * dv), (half_t)(acc[3] * dv)};
    *(half4v*)&aggx[n * 16 + sub] = o;
}

// aggx [N,16(9)] fp16 @ w0 [9,128] -> gf fp16 + fused stats partials
__global__ __launch_bounds__(256) void k_mm9(const half_t* __restrict__ aggx,
        const float* __restrict__ w0, half_t* __restrict__ gout,
        float* __restrict__ ps, float* __restrict__ ps2) {
    __shared__ float lsum[4][128], lsq[4][128];
    int t = threadIdx.x, w = t >> 6, l = t & 63;
    int c = 2 * l;
    int n0 = blockIdx.x * CH_MM;
    int n1 = min(NN, n0 + CH_MM);
    float s0 = 0.f, s1 = 0.f, q0 = 0.f, q1 = 0.f;
    for (int n = n0 + w; n < n1; n += 4) {
        float2 acc = make_float2(0.f, 0.f);
#pragma unroll
        for (int k = 0; k < 9; ++k) {
            float a = (float)aggx[n * 16 + k];
            float2 wv = *(const float2*)&w0[k * HD + c];
            acc.x += a * wv.x;
            acc.y += a * wv.y;
        }
        half_t hx = (half_t)acc.x, hy = (half_t)acc.y;
        half2v hv = {hx, hy};
        *(half2v*)&gout[n * HD + c] = hv;
        float fx = (float)hx, fy = (float)hy;
        s0 += fx; q0 += fx * fx; s1 += fy; q1 += fy * fy;
    }
    lsum[w][c] = s0; lsum[w][c + 1] = s1;
    lsq[w][c] = q0;  lsq[w][c + 1] = q1;
    __syncthreads();
    if (t < 128) {
        ps[blockIdx.x * 128 + t] = lsum[0][t] + lsum[1][t] + lsum[2][t] + lsum[3][t];
        ps2[blockIdx.x * 128 + t] = lsq[0][t] + lsq[1][t] + lsq[2][t] + lsq[3][t];
    }
}

// one block per channel, tree-reduce nb partials
__global__ __launch_bounds__(256) void k_stats2(const float* __restrict__ ps,
        const float* __restrict__ ps2, const float* __restrict__ g,
        const float* __restrict__ be, float* __restrict__ scale,
        float* __restrict__ shift, int nb) {
    __shared__ float sa[256], sb[256];
    int c = blockIdx.x, t = threadIdx.x;
    float S = 0.f, Q = 0.f;
    for (int i = t; i < nb; i += 256) {
        S += ps[i * 128 + c];
        Q += ps2[i * 128 + c];
    }
    sa[t] = S; sb[t] = Q;
    __syncthreads();
    for (int o = 128; o; o >>= 1) {
        if (t < o) { sa[t] += sa[t + o]; sb[t] += sb[t + o]; }
        __syncthreads();
    }
    if (t == 0) {
        double mu = (double)sa[0] / NN;
        double var = (double)sb[0] / NN - mu * mu;
        float sc = g[c] * rsqrtf((float)var + EPSV);
        scale[c] = sc;
        shift[c] = be[c] - (float)mu * sc;
    }
}

// ---------------- MFMA matmul: hh = relu(bn(gf)) @ W · dinv, fp16 out ----------------

__global__ __launch_bounds__(256) void k_mm_mfma(const half_t* __restrict__ gf,
        const float* __restrict__ scale, const float* __restrict__ shift,
        const float* __restrict__ dinv, const half_t* __restrict__ Wt,
        half_t* __restrict__ hh) {
    __shared__ half_t wlds[16384];   // [n][k] fp16, 16B-XOR swizzled
    int t = threadIdx.x;
#pragma unroll
    for (int j = 0; j < 8; ++j) {
        int cidx = t * 8 + j;          // 16-B chunk
        int n = cidx >> 4, k8 = cidx & 15;
        half8 v = *(const half8*)&Wt[cidx * 8];
        int byte = n * 256 + ((k8 * 16) ^ ((n & 7) << 4));
        *(half8*)((char*)wlds + byte) = v;
    }
    __syncthreads();
    int w = t >> 6, l = t & 63;
    int lr = l & 15, lg = l >> 4;
    int base = (blockIdx.x * 4 + w) * 16;
    int row = base + lr;
    bool rowok = row < NN;
    f32x4 acc[8];
#pragma unroll
    for (int nt = 0; nt < 8; ++nt) acc[nt] = (f32x4){0.f, 0.f, 0.f, 0.f};
#pragma unroll
    for (int kk = 0; kk < 4; ++kk) {
        int ch0 = kk * 32 + lg * 8;
        half8 a8;
        if (rowok) {
            half8 hv = *(const half8*)&gf[row * HD + ch0];
            f32x4 sc0 = *(const f32x4*)&scale[ch0];
            f32x4 sc1 = *(const f32x4*)&scale[ch0 + 4];
            f32x4 sh0 = *(const f32x4*)&shift[ch0];
            f32x4 sh1 = *(const f32x4*)&shift[ch0 + 4];
#pragma unroll
            for (int i = 0; i < 4; ++i)
                a8[i] = (half_t)fmaxf((float)hv[i] * sc0[i] + sh0[i], 0.f);
#pragma unroll
            for (int i = 0; i < 4; ++i)
                a8[4 + i] = (half_t)fmaxf((float)hv[4 + i] * sc1[i] + sh1[i], 0.f);
        } else {
#pragma unroll
            for (int i = 0; i < 8; ++i) a8[i] = (half_t)0.f;
        }
        int kbyte = kk * 64 + lg * 16;
#pragma unroll
        for (int nt = 0; nt < 8; ++nt) {
            int n = nt * 16 + lr;
            half8 b8 = *(const half8*)((const char*)wlds + n * 256 + (kbyte ^ ((n & 7) << 4)));
            acc[nt] = __builtin_amdgcn_mfma_f32_16x16x32_f16(a8, b8, acc[nt], 0, 0, 0);
        }
    }
#pragma unroll
    for (int i = 0; i < 4; ++i) {
        int r = base + lg * 4 + i;
        if (r < NN) {
            float dv = dinv[r];
#pragma unroll
            for (int nt = 0; nt < 8; ++nt)
                hh[r * HD + nt * 16 + lr] = (half_t)(acc[nt][i] * dv);
        }
    }
}

// ---------------- fp16 CSR gather (round-5 exact) + fused stats ----------------

__global__ __launch_bounds__(256) void k_agg_h(const half_t* __restrict__ hh,
        const float* __restrict__ dinv, half_t* __restrict__ gout,
        const int* __restrict__ rp, const int* __restrict__ col,
        float* __restrict__ ps, float* __restrict__ ps2) {
    __shared__ float lsum[16][128], lsq[16][128];
    int t = threadIdx.x, w = t >> 6, l = t & 63;
    int sub = l >> 4, li = l & 15;
    int sg = w * 4 + sub;             // 0..15
    int c0 = li * 8;
    int n0 = blockIdx.x * CH_AG;
    int n1 = min(NN, n0 + CH_AG);
    float sacc[8], qacc[8];
#pragma unroll
    for (int j = 0; j < 8; ++j) { sacc[j] = 0.f; qacc[j] = 0.f; }
    for (int n = n0 + sg; n < n1; n += 16) {
        int s = rp[n], e = rp[n + 1];
        float facc[8];
#pragma unroll
        for (int j = 0; j < 8; ++j) facc[j] = 0.f;
        int i = s;
        for (; i + 1 < e; i += 2) {
            int ca = col[i], cb = col[i + 1];
            half8 v0 = *(const half8*)&hh[ca * HD + c0];
            half8 v1 = *(const half8*)&hh[cb * HD + c0];
#pragma unroll
            for (int j = 0; j < 8; ++j) facc[j] += (float)v0[j] + (float)v1[j];
        }
        if (i < e) {
            half8 v0 = *(const half8*)&hh[col[i] * HD + c0];
#pragma unroll
            for (int j = 0; j < 8; ++j) facc[j] += (float)v0[j];
        }
        float dv = dinv[n];
        half8 hv;
#pragma unroll
        for (int j = 0; j < 8; ++j) hv[j] = (half_t)(facc[j] * dv);
        *(half8*)&gout[n * HD + c0] = hv;
#pragma unroll
        for (int j = 0; j < 8; ++j) {
            float f = (float)hv[j];
            sacc[j] += f;
            qacc[j] += f * f;
        }
    }
#pragma unroll
    for (int j = 0; j < 8; ++j) {
        lsum[sg][c0 + j] = sacc[j];
        lsq[sg][c0 + j] = qacc[j];
    }
    __syncthreads();
    if (t < 128) {
        float S = 0.f, Q = 0.f;
#pragma unroll
        for (int g = 0; g < 16; ++g) { S += lsum[g][t]; Q += lsq[g][t]; }
        ps[blockIdx.x * 128 + t] = S;
        ps2[blockIdx.x * 128 + t] = Q;
    }
}

// ---------------- fused pool (final BN+ReLU) + MLP ----------------

#define GPB 8
__global__ __launch_bounds__(256) void k_poolmlp(const half_t* __restrict__ h,
        const float* __restrict__ scale, const float* __restrict__ shift,
        const int* __restrict__ batch,
        const float* __restrict__ m0w, const float* __restrict__ m0b,
        const float* __restrict__ m1w, const float* __restrict__ m1b,
        const float* __restrict__ m2w, const float* __restrict__ m2b,
        float* __restrict__ out) {
    __shared__ float xs[GPB][256];
    __shared__ float h1[GPB][256];
    __shared__ float h2[GPB][64];
    int t = threadIdx.x, w = t >> 6, l = t & 63;
    int g0 = blockIdx.x * GPB;
    int c = 2 * l;
    float2 sc2 = make_float2(scale[c], scale[c + 1]);
    float2 sh2 = make_float2(shift[c], shift[c + 1]);
    // pool phase: each wave pools 2 graphs
#pragma unroll
    for (int rep = 0; rep < 2; ++rep) {
        int j = w * 2 + rep;
        int g = g0 + j;
        int lo = 0, hi = NN;
        while (lo < hi) { int m = (lo + hi) >> 1; if (batch[m] < g) lo = m + 1; else hi = m; }
        int s = lo;
        hi = NN;
        while (lo < hi) { int m = (lo + hi) >> 1; if (batch[m] < g + 1) lo = m + 1; else hi = m; }
        int e = lo;
        float2 sum = make_float2(0.f, 0.f), mx = make_float2(-3e38f, -3e38f);
        for (int r = s; r < e; ++r) {
            half2v hv = *(const half2v*)&h[r * HD + c];
            float vx = fmaxf((float)hv[0] * sc2.x + sh2.x, 0.f);
            float vy = fmaxf((float)hv[1] * sc2.y + sh2.y, 0.f);
            sum.x += vx; sum.y += vy;
            mx.x = fmaxf(mx.x, vx); mx.y = fmaxf(mx.y, vy);
        }
        float2 mean = make_float2(0.f, 0.f), mxo = make_float2(0.f, 0.f);
        if (e > s) {
            float cnt = (float)(e - s);
            mean.x = sum.x / cnt; mean.y = sum.y / cnt;
            mxo = mx;
        }
        xs[j][c] = mean.x; xs[j][c + 1] = mean.y;
        xs[j][128 + c] = mxo.x; xs[j][128 + c + 1] = mxo.y;
    }
    __syncthreads();
    // MLP phase
    float acc[GPB];
#pragma unroll
    for (int j = 0; j < GPB; ++j) acc[j] = m0b[t];
    for (int i = 0; i < 256; ++i) {
        float wv = m0w[i * 256 + t];
#pragma unroll
        for (int j = 0; j < GPB; ++j) acc[j] += xs[j][i] * wv;
    }
#pragma unroll
    for (int j = 0; j < GPB; ++j) h1[j][t] = fmaxf(acc[j], 0.f);
    __syncthreads();
    if (t < 64) {
        float a2[GPB];
#pragma unroll
        for (int j = 0; j < GPB; ++j) a2[j] = m1b[t];
        for (int i = 0; i < 256; ++i) {
            float wv = m1w[i * 64 + t];
#pragma unroll
            for (int j = 0; j < GPB; ++j) a2[j] += h1[j][i] * wv;
        }
#pragma unroll
        for (int j = 0; j < GPB; ++j) h2[j][t] = fmaxf(a2[j], 0.f);
    }
    __syncthreads();
    if (t < 64) {
#pragma unroll
        for (int j = 0; j < GPB; ++j) {
            float v = h2[j][t] * m2w[t];
            for (int off = 32; off; off >>= 1) v += __shfl_down(v, off);
            if (t == 0) out[g0 + j] = v + m2b[0];
        }
    }
}

// ---------------- launch ----------------

extern "C" void kernel_launch(void* const* d_in, const int* in_sizes, int n_in,
                              void* d_out, int out_size, void* d_ws, size_t ws_size,
                              hipStream_t stream) {
    const float* x    = (const float*)d_in[0];
    const int*   ei   = (const int*)d_in[1];
    const int*   batch= (const int*)d_in[2];
    const float* w0   = (const float*)d_in[3];
    const float* w12  = (const float*)d_in[4];
    // d_in[5] = cb : cancelled by BN mean-subtraction
    const float* bn_g = (const float*)d_in[6];
    const float* bn_b = (const float*)d_in[7];
    const float* m0w  = (const float*)d_in[8];
    const float* m0b  = (const float*)d_in[9];
    const float* m1w  = (const float*)d_in[10];
    const float* m1b  = (const float*)d_in[11];
    const float* m2w  = (const float*)d_in[12];
    const float* m2b  = (const float*)d_in[13];
    float* out = (float*)d_out;

    char* p = (char*)d_ws;
    auto alloc = [&](size_t bytes) {
        void* r = (void*)p;
        p += (bytes + 255) & ~(size_t)255;
        return r;
    };
    half_t*   gf0    = (half_t*)alloc((size_t)NN * HD * 2);
    half_t*   gf1    = (half_t*)alloc((size_t)NN * HD * 2);
    half_t*   hh     = (half_t*)alloc((size_t)NN * HD * 2);
    half_t*   xh     = (half_t*)alloc((size_t)NN * 16 * 2);
    half_t*   aggx   = (half_t*)alloc((size_t)NN * 16 * 2);
    half_t*   Wt     = (half_t*)alloc((size_t)2 * 128 * 128 * 2);
    float*    dinv   = (float*)alloc((size_t)NN * 4);
    int*      rp     = (int*)alloc((size_t)(NN + 1) * 4);
    int*      col    = (int*)alloc((size_t)(NE + NN) * 4);
    unsigned* binned = (unsigned*)alloc((size_t)NE * 4);
    int*      bcnt   = (int*)alloc(512 * 4);
    int*      ebase  = (int*)alloc(512 * 4);
    int*      gcur   = (int*)alloc(512 * 4);
    float*    ps     = (float*)alloc((size_t)NB_AG * 128 * 4);
    float*    ps2    = (float*)alloc((size_t)NB_AG * 128 * 4);
    float*    scb    = (float*)alloc(3 * 128 * 4);
    float*    shb    = (float*)alloc(3 * 128 * 4);

    // ---- CSR build ----
    k_zero_i32<<<2, 256, 0, stream>>>(bcnt, 512);
    k_bcount<<<NBIN_BLK, 256, 0, stream>>>(ei, bcnt);
    k_bscan<<<1, 512, 0, stream>>>(bcnt, ebase, gcur);
    k_bin<<<NBIN_BLK, 256, 0, stream>>>(ei, gcur, binned);
    k_csr<<<NBUCK, 256, 0, stream>>>(binned, ebase, rp, dinv, col);

    // ---- prep (Wt cvt + x pad) ----
    k_prep<<<128 + (NN + 255) / 256, 256, 0, stream>>>(w12, Wt, x, dinv, xh);

    // ---- layer 0 ----
    k_aggx<<<(NN * 4 + 255) / 256, 256, 0, stream>>>(xh, dinv, aggx, rp, col);
    k_mm9<<<NB_MM, 256, 0, stream>>>(aggx, w0, gf0, ps, ps2);
    k_stats2<<<128, 256, 0, stream>>>(ps, ps2, bn_g + 0, bn_b + 0, scb + 0, shb + 0, NB_MM);

    // ---- layer 1 ----
    k_mm_mfma<<<(NN + 63) / 64, 256, 0, stream>>>(gf0, scb + 0, shb + 0, dinv, Wt, hh);
    k_agg_h<<<NB_AG, 256, 0, stream>>>(hh, dinv, gf1, rp, col, ps, ps2);
    k_stats2<<<128, 256, 0, stream>>>(ps, ps2, bn_g + 128, bn_b + 128, scb + 128, shb + 128, NB_AG);

    // ---- layer 2 ----
    k_mm_mfma<<<(NN + 63) / 64, 256, 0, stream>>>(gf1, scb + 128, shb + 128, dinv, Wt + 16384, hh);
    k_agg_h<<<NB_AG, 256, 0, stream>>>(hh, dinv, gf0, rp, col, ps, ps2);
    k_stats2<<<128, 256, 0, stream>>>(ps, ps2, bn_g + 256, bn_b + 256, scb + 256, shb + 256, NB_AG);

    // ---- fused pool + MLP ----
    k_poolmlp<<<NG / GPB, 256, 0, stream>>>(gf0, scb + 256, shb + 256, batch,
                                            m0w, m0b, m1w, m1b, m2w, m2b, out);
}

// Round 9
// 361.083 us; speedup vs baseline: 1.0726x; 1.0288x over previous
//
#include <hip/hip_runtime.h>

#define NN 100000
#define NE 1600000
#define NG 4096
#define HD 128
#define EPSV 1e-5f
#define NBUCK 391            // ceil(NN/256)
#define BIN_CHUNK 4096
#define NBIN_BLK ((NE + BIN_CHUNK - 1) / BIN_CHUNK)   // 391
#define CSR_CAP 8448
#define NB_AG 4096           // agg stats blocks
#define CH_AG 25             // ceil(NN/NB_AG)
#define NB_MM 2048           // mm9 stats blocks
#define CH_MM 49             // ceil(NN/NB_MM)

typedef _Float16 half_t;
typedef _Float16 half8 __attribute__((ext_vector_type(8)));
typedef _Float16 half4v __attribute__((ext_vector_type(4)));
typedef _Float16 half2v __attribute__((ext_vector_type(2)));
typedef float f32x4 __attribute__((ext_vector_type(4)));

// ---------------- bucketed CSR build ----------------

__global__ void k_zero_i32(int* p, int n) {
    int i = blockIdx.x * blockDim.x + threadIdx.x;
    if (i < n) p[i] = 0;
}

__global__ void k_bcount(const int* __restrict__ ei, int* __restrict__ bcnt) {
    __shared__ int cnt[NBUCK];
    int t = threadIdx.x;
    for (int i = t; i < NBUCK; i += 256) cnt[i] = 0;
    __syncthreads();
    int e0 = blockIdx.x * BIN_CHUNK;
    int e1 = min(NE, e0 + BIN_CHUNK);
    for (int e = e0 + t; e < e1; e += 256)
        atomicAdd(&cnt[ei[NE + e] >> 8], 1);
    __syncthreads();
    for (int i = t; i < NBUCK; i += 256)
        if (cnt[i]) atomicAdd(&bcnt[i], cnt[i]);
}

__global__ void k_bscan(const int* __restrict__ bcnt, int* __restrict__ ebase, int* __restrict__ gcur) {
    __shared__ int s[512];
    int t = threadIdx.x;
    int v = (t < NBUCK) ? bcnt[t] : 0;
    s[t] = v;
    __syncthreads();
    for (int off = 1; off < 512; off <<= 1) {
        int x = (t >= off) ? s[t - off] : 0;
        __syncthreads();
        s[t] += x;
        __syncthreads();
    }
    if (t <= NBUCK) {
        int ex = s[t] - v;
        ebase[t] = ex;
        if (t < NBUCK) gcur[t] = ex;
    }
}

__global__ void k_bin(const int* __restrict__ ei, int* __restrict__ gcur, unsigned* __restrict__ binned) {
    __shared__ int cnt[NBUCK];
    __shared__ int cur[NBUCK];
    int t = threadIdx.x;
    for (int i = t; i < NBUCK; i += 256) cnt[i] = 0;
    __syncthreads();
    int e0 = blockIdx.x * BIN_CHUNK;
    int e1 = min(NE, e0 + BIN_CHUNK);
    for (int e = e0 + t; e < e1; e += 256)
        atomicAdd(&cnt[ei[NE + e] >> 8], 1);
    __syncthreads();
    for (int i = t; i < NBUCK; i += 256)
        cur[i] = cnt[i] ? atomicAdd(&gcur[i], cnt[i]) : 0;
    __syncthreads();
    for (int e = e0 + t; e < e1; e += 256) {
        int d = ei[NE + e];
        int b = d >> 8;
        int r = atomicAdd(&cur[b], 1);
        binned[r] = ((unsigned)ei[e] << 8) | (unsigned)(d & 255);
    }
}

__global__ __launch_bounds__(256) void k_csr(const unsigned* __restrict__ binned,
        const int* __restrict__ ebase, int* __restrict__ rp,
        float* __restrict__ dinv, int* __restrict__ col) {
    __shared__ int colb[CSR_CAP];
    __shared__ int deg[256], cur[256], s[256];
    int b = blockIdx.x, t = threadIdx.x;
    int n0 = b * 256;
    int nodes = min(256, NN - n0);
    int cbeg = ebase[b];
    int cnt_b = min(ebase[b + 1] - cbeg, CSR_CAP - 256);
    int base = cbeg + n0;
    deg[t] = 0;
    __syncthreads();
    for (int i = t; i < cnt_b; i += 256)
        atomicAdd(&deg[binned[cbeg + i] & 255], 1);
    __syncthreads();
    int w = (t < nodes) ? deg[t] + 1 : 0;
    s[t] = w;
    __syncthreads();
    for (int o = 1; o < 256; o <<= 1) {
        int x = (t >= o) ? s[t - o] : 0;
        __syncthreads();
        s[t] += x;
        __syncthreads();
    }
    int ex = s[t] - w;
    cur[t] = ex;
    if (t < nodes) {
        rp[n0 + t] = base + ex;
        dinv[n0 + t] = rsqrtf((float)(deg[t] + 1));
    }
    __syncthreads();
    for (int i = t; i < cnt_b; i += 256) {
        unsigned pk = binned[cbeg + i];
        int d = pk & 255;
        int r = atomicAdd(&cur[d], 1);
        colb[r] = (int)(pk >> 8);
    }
    __syncthreads();
    if (t < nodes) colb[cur[t]] = n0 + t;
    __syncthreads();
    int tot = cnt_b + nodes;
    for (int i = t; i < tot; i += 256) col[base + i] = colb[i];
    if (b == 0 && t == 0) rp[NN] = NE + NN;
}

// ---------------- fused prep: Wt transpose-cvt + x pad/scale + graph bounds ----------------

__global__ void k_prep(const float* __restrict__ w12, half_t* __restrict__ Wt,
                       const float* __restrict__ x, const float* __restrict__ dinv,
                       half_t* __restrict__ xh, const int* __restrict__ batch,
                       int* __restrict__ gstart) {
    int b = blockIdx.x;
    if (b < 16) {            // gbound: 16*256 = 4096 graphs
        int g = b * 256 + threadIdx.x;
        int lo = 0, hi = NN;
        while (lo < hi) { int m = (lo + hi) >> 1; if (batch[m] < g) lo = m + 1; else hi = m; }
        gstart[g] = lo;
        if (g == 0) gstart[NG] = NN;
    } else if (b < 144) {    // cvtw: 128 blocks x 256 = 32768
        int i = (b - 16) * 256 + threadIdx.x;
        int m = i >> 14;
        int r = i & 16383;
        int n = r >> 7, k = r & 127;
        Wt[i] = (half_t)w12[m * 16384 + k * 128 + n];
    } else {                 // padx
        int n = (b - 144) * 256 + threadIdx.x;
        if (n >= NN) return;
        float dv = dinv[n];
        half_t buf[16];
#pragma unroll
        for (int k = 0; k < 9; ++k) buf[k] = (half_t)(x[n * 9 + k] * dv);
#pragma unroll
        for (int k = 9; k < 16; ++k) buf[k] = (half_t)0.f;
        *(half8*)&xh[n * 16] = *(half8*)buf;
        *(half8*)&xh[n * 16 + 8] = *(half8*)(buf + 8);
    }
}

// ---------------- layer 0 ----------------

// 4 lanes per node, half4 (8B) per lane; fp16 out
__global__ void k_aggx(const half_t* __restrict__ xh, const float* __restrict__ dinv,
                       half_t* __restrict__ aggx,
                       const int* __restrict__ rp, const int* __restrict__ col) {
    int t = blockIdx.x * blockDim.x + threadIdx.x;
    int n = t >> 2, sub = (t & 3) * 4;
    if (n >= NN) return;
    int s = rp[n], e = rp[n + 1];
    float acc[4] = {0.f, 0.f, 0.f, 0.f};
    int i = s;
    for (; i + 1 < e; i += 2) {
        half4v v0 = *(const half4v*)&xh[col[i] * 16 + sub];
        half4v v1 = *(const half4v*)&xh[col[i + 1] * 16 + sub];
#pragma unroll
        for (int j = 0; j < 4; ++j) acc[j] += (float)v0[j] + (float)v1[j];
    }
    if (i < e) {
        half4v v0 = *(const half4v*)&xh[col[i] * 16 + sub];
#pragma unroll
        for (int j = 0; j < 4; ++j) acc[j] += (float)v0[j];
    }
    float dv = dinv[n];
    half4v o = {(half_t)(acc[0] * dv), (half_t)(acc[1] * dv),
                (half_t)(acc[2] * dv), (half_t)(acc[3] * dv)};
    *(half4v*)&aggx[n * 16 + sub] = o;
}

// aggx [N,16(9)] fp16 @ w0 [9,128] -> gf fp16 + fused stats partials
__global__ __launch_bounds__(256) void k_mm9(const half_t* __restrict__ aggx,
        const float* __restrict__ w0, half_t* __restrict__ gout,
        float* __restrict__ ps, float* __restrict__ ps2) {
    __shared__ float lsum[4][128], lsq[4][128];
    int t = threadIdx.x, w = t >> 6, l = t & 63;
    int c = 2 * l;
    int n0 = blockIdx.x * CH_MM;
    int n1 = min(NN, n0 + CH_MM);
    float s0 = 0.f, s1 = 0.f, q0 = 0.f, q1 = 0.f;
    for (int n = n0 + w; n < n1; n += 4) {
        float2 acc = make_float2(0.f, 0.f);
#pragma unroll
        for (int k = 0; k < 9; ++k) {
            float a = (float)aggx[n * 16 + k];
            float2 wv = *(const float2*)&w0[k * HD + c];
            acc.x += a * wv.x;
            acc.y += a * wv.y;
        }
        half_t hx = (half_t)acc.x, hy = (half_t)acc.y;
        half2v hv = {hx, hy};
        *(half2v*)&gout[n * HD + c] = hv;
        float fx = (float)hx, fy = (float)hy;
        s0 += fx; q0 += fx * fx; s1 += fy; q1 += fy * fy;
    }
    lsum[w][c] = s0; lsum[w][c + 1] = s1;
    lsq[w][c] = q0;  lsq[w][c + 1] = q1;
    __syncthreads();
    if (t < 128) {
        ps[blockIdx.x * 128 + t] = lsum[0][t] + lsum[1][t] + lsum[2][t] + lsum[3][t];
        ps2[blockIdx.x * 128 + t] = lsq[0][t] + lsq[1][t] + lsq[2][t] + lsq[3][t];
    }
}

// one block per channel, tree-reduce nb partials
__global__ __launch_bounds__(256) void k_stats2(const float* __restrict__ ps,
        const float* __restrict__ ps2, const float* __restrict__ g,
        const float* __restrict__ be, float* __restrict__ scale,
        float* __restrict__ shift, int nb) {
    __shared__ float sa[256], sb[256];
    int c = blockIdx.x, t = threadIdx.x;
    float S = 0.f, Q = 0.f;
    for (int i = t; i < nb; i += 256) {
        S += ps[i * 128 + c];
        Q += ps2[i * 128 + c];
    }
    sa[t] = S; sb[t] = Q;
    __syncthreads();
    for (int o = 128; o; o >>= 1) {
        if (t < o) { sa[t] += sa[t + o]; sb[t] += sb[t + o]; }
        __syncthreads();
    }
    if (t == 0) {
        double mu = (double)sa[0] / NN;
        double var = (double)sb[0] / NN - mu * mu;
        float sc = g[c] * rsqrtf((float)var + EPSV);
        scale[c] = sc;
        shift[c] = be[c] - (float)mu * sc;
    }
}

// ---------------- MFMA matmul: hh = relu(bn(gf)) @ W · dinv, fp16 out ----------------

__global__ __launch_bounds__(256) void k_mm_mfma(const half_t* __restrict__ gf,
        const float* __restrict__ scale, const float* __restrict__ shift,
        const float* __restrict__ dinv, const half_t* __restrict__ Wt,
        half_t* __restrict__ hh) {
    __shared__ half_t wlds[16384];   // [n][k] fp16, 16B-XOR swizzled
    int t = threadIdx.x;
#pragma unroll
    for (int j = 0; j < 8; ++j) {
        int cidx = t * 8 + j;          // 16-B chunk
        int n = cidx >> 4, k8 = cidx & 15;
        half8 v = *(const half8*)&Wt[cidx * 8];
        int byte = n * 256 + ((k8 * 16) ^ ((n & 7) << 4));
        *(half8*)((char*)wlds + byte) = v;
    }
    __syncthreads();
    int w = t >> 6, l = t & 63;
    int lr = l & 15, lg = l >> 4;
    int base = (blockIdx.x * 4 + w) * 16;
    int row = base + lr;
    bool rowok = row < NN;
    f32x4 acc[8];
#pragma unroll
    for (int nt = 0; nt < 8; ++nt) acc[nt] = (f32x4){0.f, 0.f, 0.f, 0.f};
#pragma unroll
    for (int kk = 0; kk < 4; ++kk) {
        int ch0 = kk * 32 + lg * 8;
        half8 a8;
        if (rowok) {
            half8 hv = *(const half8*)&gf[row * HD + ch0];
            f32x4 sc0 = *(const f32x4*)&scale[ch0];
            f32x4 sc1 = *(const f32x4*)&scale[ch0 + 4];
            f32x4 sh0 = *(const f32x4*)&shift[ch0];
            f32x4 sh1 = *(const f32x4*)&shift[ch0 + 4];
#pragma unroll
            for (int i = 0; i < 4; ++i)
                a8[i] = (half_t)fmaxf((float)hv[i] * sc0[i] + sh0[i], 0.f);
#pragma unroll
            for (int i = 0; i < 4; ++i)
                a8[4 + i] = (half_t)fmaxf((float)hv[4 + i] * sc1[i] + sh1[i], 0.f);
        } else {
#pragma unroll
            for (int i = 0; i < 8; ++i) a8[i] = (half_t)0.f;
        }
        int kbyte = kk * 64 + lg * 16;
#pragma unroll
        for (int nt = 0; nt < 8; ++nt) {
            int n = nt * 16 + lr;
            half8 b8 = *(const half8*)((const char*)wlds + n * 256 + (kbyte ^ ((n & 7) << 4)));
            acc[nt] = __builtin_amdgcn_mfma_f32_16x16x32_f16(a8, b8, acc[nt], 0, 0, 0);
        }
    }
#pragma unroll
    for (int i = 0; i < 4; ++i) {
        int r = base + lg * 4 + i;
        if (r < NN) {
            float dv = dinv[r];
#pragma unroll
            for (int nt = 0; nt < 8; ++nt)
                hh[r * HD + nt * 16 + lr] = (half_t)(acc[nt][i] * dv);
        }
    }
}

// ---------------- fp16 CSR gather (round-5 exact) + fused stats ----------------

__global__ __launch_bounds__(256) void k_agg_h(const half_t* __restrict__ hh,
        const float* __restrict__ dinv, half_t* __restrict__ gout,
        const int* __restrict__ rp, const int* __restrict__ col,
        float* __restrict__ ps, float* __restrict__ ps2) {
    __shared__ float lsum[16][128], lsq[16][128];
    int t = threadIdx.x, w = t >> 6, l = t & 63;
    int sub = l >> 4, li = l & 15;
    int sg = w * 4 + sub;             // 0..15
    int c0 = li * 8;
    int n0 = blockIdx.x * CH_AG;
    int n1 = min(NN, n0 + CH_AG);
    float sacc[8], qacc[8];
#pragma unroll
    for (int j = 0; j < 8; ++j) { sacc[j] = 0.f; qacc[j] = 0.f; }
    for (int n = n0 + sg; n < n1; n += 16) {
        int s = rp[n], e = rp[n + 1];
        float facc[8];
#pragma unroll
        for (int j = 0; j < 8; ++j) facc[j] = 0.f;
        int i = s;
        for (; i + 1 < e; i += 2) {
            int ca = col[i], cb = col[i + 1];
            half8 v0 = *(const half8*)&hh[ca * HD + c0];
            half8 v1 = *(const half8*)&hh[cb * HD + c0];
#pragma unroll
            for (int j = 0; j < 8; ++j) facc[j] += (float)v0[j] + (float)v1[j];
        }
        if (i < e) {
            half8 v0 = *(const half8*)&hh[col[i] * HD + c0];
#pragma unroll
            for (int j = 0; j < 8; ++j) facc[j] += (float)v0[j];
        }
        float dv = dinv[n];
        half8 hv;
#pragma unroll
        for (int j = 0; j < 8; ++j) hv[j] = (half_t)(facc[j] * dv);
        *(half8*)&gout[n * HD + c0] = hv;
#pragma unroll
        for (int j = 0; j < 8; ++j) {
            float f = (float)hv[j];
            sacc[j] += f;
            qacc[j] += f * f;
        }
    }
#pragma unroll
    for (int j = 0; j < 8; ++j) {
        lsum[sg][c0 + j] = sacc[j];
        lsq[sg][c0 + j] = qacc[j];
    }
    __syncthreads();
    if (t < 128) {
        float S = 0.f, Q = 0.f;
#pragma unroll
        for (int g = 0; g < 16; ++g) { S += lsum[g][t]; Q += lsq[g][t]; }
        ps[blockIdx.x * 128 + t] = S;
        ps2[blockIdx.x * 128 + t] = Q;
    }
}

// ---------------- pooling (bounds precomputed) + MLP ----------------

__global__ void k_pool(const half_t* __restrict__ h, const float* __restrict__ scale,
                       const float* __restrict__ shift, const int* __restrict__ gstart,
                       float* __restrict__ xg) {
    int l = threadIdx.x & 63;
    int g = blockIdx.x * (blockDim.x >> 6) + (threadIdx.x >> 6);
    if (g >= NG) return;
    int c = 2 * l;
    float2 sc = make_float2(scale[c], scale[c + 1]);
    float2 sh = make_float2(shift[c], shift[c + 1]);
    int s = gstart[g], e = gstart[g + 1];
    float2 sum = make_float2(0.f, 0.f), mx = make_float2(-3e38f, -3e38f);
    for (int r = s; r < e; ++r) {
        half2v hv = *(const half2v*)&h[r * HD + c];
        float vx = fmaxf((float)hv[0] * sc.x + sh.x, 0.f);
        float vy = fmaxf((float)hv[1] * sc.y + sh.y, 0.f);
        sum.x += vx; sum.y += vy;
        mx.x = fmaxf(mx.x, vx); mx.y = fmaxf(mx.y, vy);
    }
    float2 mean = make_float2(0.f, 0.f), mxo = make_float2(0.f, 0.f);
    if (e > s) {
        float cnt = (float)(e - s);
        mean.x = sum.x / cnt; mean.y = sum.y / cnt;
        mxo = mx;
    }
    *(float2*)&xg[g * 256 + c] = mean;
    *(float2*)&xg[g * 256 + 128 + c] = mxo;
}

#define GPB 8
__global__ __launch_bounds__(256) void k_mlp(const float* __restrict__ xg,
                                             const float* __restrict__ m0w, const float* __restrict__ m0b,
                                             const float* __restrict__ m1w, const float* __restrict__ m1b,
                                             const float* __restrict__ m2w, const float* __restrict__ m2b,
                                             float* __restrict__ out) {
    __shared__ float xs[GPB][256];
    __shared__ float h1[GPB][256];
    __shared__ float h2[GPB][64];
    int t = threadIdx.x;
    int g0 = blockIdx.x * GPB;
#pragma unroll
    for (int j = 0; j < GPB; ++j) xs[j][t] = xg[(g0 + j) * 256 + t];
    __syncthreads();
    float acc[GPB];
#pragma unroll
    for (int j = 0; j < GPB; ++j) acc[j] = m0b[t];
    for (int i = 0; i < 256; ++i) {
        float wv = m0w[i * 256 + t];
#pragma unroll
        for (int j = 0; j < GPB; ++j) acc[j] += xs[j][i] * wv;
    }
#pragma unroll
    for (int j = 0; j < GPB; ++j) h1[j][t] = fmaxf(acc[j], 0.f);
    __syncthreads();
    if (t < 64) {
        float a2[GPB];
#pragma unroll
        for (int j = 0; j < GPB; ++j) a2[j] = m1b[t];
        for (int i = 0; i < 256; ++i) {
            float wv = m1w[i * 64 + t];
#pragma unroll
            for (int j = 0; j < GPB; ++j) a2[j] += h1[j][i] * wv;
        }
#pragma unroll
        for (int j = 0; j < GPB; ++j) h2[j][t] = fmaxf(a2[j], 0.f);
    }
    __syncthreads();
    if (t < 64) {
#pragma unroll
        for (int j = 0; j < GPB; ++j) {
            float v = h2[j][t] * m2w[t];
            for (int off = 32; off; off >>= 1) v += __shfl_down(v, off);
            if (t == 0) out[g0 + j] = v + m2b[0];
        }
    }
}

// ---------------- launch ----------------

extern "C" void kernel_launch(void* const* d_in, const int* in_sizes, int n_in,
                              void* d_out, int out_size, void* d_ws, size_t ws_size,
                              hipStream_t stream) {
    const float* x    = (const float*)d_in[0];
    const int*   ei   = (const int*)d_in[1];
    const int*   batch= (const int*)d_in[2];
    const float* w0   = (const float*)d_in[3];
    const float* w12  = (const float*)d_in[4];
    // d_in[5] = cb : cancelled by BN mean-subtraction
    const float* bn_g = (const float*)d_in[6];
    const float* bn_b = (const float*)d_in[7];
    const float* m0w  = (const float*)d_in[8];
    const float* m0b  = (const float*)d_in[9];
    const float* m1w  = (const float*)d_in[10];
    const float* m1b  = (const float*)d_in[11];
    const float* m2w  = (const float*)d_in[12];
    const float* m2b  = (const float*)d_in[13];
    float* out = (float*)d_out;

    char* p = (char*)d_ws;
    auto alloc = [&](size_t bytes) {
        void* r = (void*)p;
        p += (bytes + 255) & ~(size_t)255;
        return r;
    };
    half_t*   gf0    = (half_t*)alloc((size_t)NN * HD * 2);
    half_t*   gf1    = (half_t*)alloc((size_t)NN * HD * 2);
    half_t*   hh     = (half_t*)alloc((size_t)NN * HD * 2);
    half_t*   xh     = (half_t*)alloc((size_t)NN * 16 * 2);
    half_t*   aggx   = (half_t*)alloc((size_t)NN * 16 * 2);
    half_t*   Wt     = (half_t*)alloc((size_t)2 * 128 * 128 * 2);
    float*    dinv   = (float*)alloc((size_t)NN * 4);
    int*      rp     = (int*)alloc((size_t)(NN + 1) * 4);
    int*      col    = (int*)alloc((size_t)(NE + NN) * 4);
    unsigned* binned = (unsigned*)alloc((size_t)NE * 4);
    int*      bcnt   = (int*)alloc(512 * 4);
    int*      ebase  = (int*)alloc(512 * 4);
    int*      gcur   = (int*)alloc(512 * 4);
    int*      gstart = (int*)alloc((size_t)(NG + 1) * 4);
    float*    ps     = (float*)alloc((size_t)NB_AG * 128 * 4);
    float*    ps2    = (float*)alloc((size_t)NB_AG * 128 * 4);
    float*    scb    = (float*)alloc(3 * 128 * 4);
    float*    shb    = (float*)alloc(3 * 128 * 4);
    float*    xg     = (float*)alloc((size_t)NG * 256 * 4);

    // ---- CSR build ----
    k_zero_i32<<<2, 256, 0, stream>>>(bcnt, 512);
    k_bcount<<<NBIN_BLK, 256, 0, stream>>>(ei, bcnt);
    k_bscan<<<1, 512, 0, stream>>>(bcnt, ebase, gcur);
    k_bin<<<NBIN_BLK, 256, 0, stream>>>(ei, gcur, binned);
    k_csr<<<NBUCK, 256, 0, stream>>>(binned, ebase, rp, dinv, col);

    // ---- prep (gbound + Wt cvt + x pad) ----
    k_prep<<<144 + (NN + 255) / 256, 256, 0, stream>>>(w12, Wt, x, dinv, xh, batch, gstart);

    // ---- layer 0 ----
    k_aggx<<<(NN * 4 + 255) / 256, 256, 0, stream>>>(xh, dinv, aggx, rp, col);
    k_mm9<<<NB_MM, 256, 0, stream>>>(aggx, w0, gf0, ps, ps2);
    k_stats2<<<128, 256, 0, stream>>>(ps, ps2, bn_g + 0, bn_b + 0, scb + 0, shb + 0, NB_MM);

    // ---- layer 1 ----
    k_mm_mfma<<<(NN + 63) / 64, 256, 0, stream>>>(gf0, scb + 0, shb + 0, dinv, Wt, hh);
    k_agg_h<<<NB_AG, 256, 0, stream>>>(hh, dinv, gf1, rp, col, ps, ps2);
    k_stats2<<<128, 256, 0, stream>>>(ps, ps2, bn_g + 128, bn_b + 128, scb + 128, shb + 128, NB_AG);

    // ---- layer 2 ----
    k_mm_mfma<<<(NN + 63) / 64, 256, 0, stream>>>(gf1, scb + 128, shb + 128, dinv, Wt + 16384, hh);
    k_agg_h<<<NB_AG, 256, 0, stream>>>(hh, dinv, gf0, rp, col, ps, ps2);
    k_stats2<<<128, 256, 0, stream>>>(ps, ps2, bn_g + 256, bn_b + 256, scb + 256, shb + 256, NB_AG);

    // ---- pool + MLP ----
    k_pool<<<NG / 4, 256, 0, stream>>>(gf0, scb + 256, shb + 256, gstart, xg);
    k_mlp<<<NG / GPB, 256, 0, stream>>>(xg, m0w, m0b, m1w, m1b, m2w, m2b, out);
}

// Round 11
// 346.655 us; speedup vs baseline: 1.1172x; 1.0416x over previous
//
#include <hip/hip_runtime.h>

#define NN 100000
#define NE 1600000
#define NG 4096
#define HD 128
#define EPSV 1e-5f
#define NBUCK 391            // ceil(NN/256)
#define BIN_CHUNK 4096
#define NBIN_BLK ((NE + BIN_CHUNK - 1) / BIN_CHUNK)   // 391
#define CSR_CAP 8448
#define NB_AG 4096           // agg stats blocks
#define CH_AG 25             // ceil(NN/NB_AG)
#define NB_L0 1563           // ceil(NN/64) fused layer-0 blocks

typedef _Float16 half_t;
typedef _Float16 half8 __attribute__((ext_vector_type(8)));
typedef _Float16 half4v __attribute__((ext_vector_type(4)));
typedef _Float16 half2v __attribute__((ext_vector_type(2)));
typedef float f32x4 __attribute__((ext_vector_type(4)));

// ---------------- bucketed CSR build ----------------

__global__ void k_zero_i32(int* p, int n) {
    int i = blockIdx.x * blockDim.x + threadIdx.x;
    if (i < n) p[i] = 0;
}

__global__ void k_bcount(const int* __restrict__ ei, int* __restrict__ bcnt) {
    __shared__ int cnt[NBUCK];
    int t = threadIdx.x;
    for (int i = t; i < NBUCK; i += 256) cnt[i] = 0;
    __syncthreads();
    int e0 = blockIdx.x * BIN_CHUNK;
    int e1 = min(NE, e0 + BIN_CHUNK);
    for (int e = e0 + t; e < e1; e += 256)
        atomicAdd(&cnt[ei[NE + e] >> 8], 1);
    __syncthreads();
    for (int i = t; i < NBUCK; i += 256)
        if (cnt[i]) atomicAdd(&bcnt[i], cnt[i]);
}

__global__ void k_bscan(const int* __restrict__ bcnt, int* __restrict__ ebase, int* __restrict__ gcur) {
    __shared__ int s[512];
    int t = threadIdx.x;
    int v = (t < NBUCK) ? bcnt[t] : 0;
    s[t] = v;
    __syncthreads();
    for (int off = 1; off < 512; off <<= 1) {
        int x = (t >= off) ? s[t - off] : 0;
        __syncthreads();
        s[t] += x;
        __syncthreads();
    }
    if (t <= NBUCK) {
        int ex = s[t] - v;
        ebase[t] = ex;
        if (t < NBUCK) gcur[t] = ex;
    }
}

__global__ void k_bin(const int* __restrict__ ei, int* __restrict__ gcur, unsigned* __restrict__ binned) {
    __shared__ int cnt[NBUCK];
    __shared__ int cur[NBUCK];
    int t = threadIdx.x;
    for (int i = t; i < NBUCK; i += 256) cnt[i] = 0;
    __syncthreads();
    int e0 = blockIdx.x * BIN_CHUNK;
    int e1 = min(NE, e0 + BIN_CHUNK);
    for (int e = e0 + t; e < e1; e += 256)
        atomicAdd(&cnt[ei[NE + e] >> 8], 1);
    __syncthreads();
    for (int i = t; i < NBUCK; i += 256)
        cur[i] = cnt[i] ? atomicAdd(&gcur[i], cnt[i]) : 0;
    __syncthreads();
    for (int e = e0 + t; e < e1; e += 256) {
        int d = ei[NE + e];
        int b = d >> 8;
        int r = atomicAdd(&cur[b], 1);
        binned[r] = ((unsigned)ei[e] << 8) | (unsigned)(d & 255);
    }
}

__global__ __launch_bounds__(256) void k_csr(const unsigned* __restrict__ binned,
        const int* __restrict__ ebase, int* __restrict__ rp,
        float* __restrict__ dinv, int* __restrict__ col) {
    __shared__ int colb[CSR_CAP];
    __shared__ int deg[256], cur[256], s[256];
    int b = blockIdx.x, t = threadIdx.x;
    int n0 = b * 256;
    int nodes = min(256, NN - n0);
    int cbeg = ebase[b];
    int cnt_b = min(ebase[b + 1] - cbeg, CSR_CAP - 256);
    int base = cbeg + n0;
    deg[t] = 0;
    __syncthreads();
    for (int i = t; i < cnt_b; i += 256)
        atomicAdd(&deg[binned[cbeg + i] & 255], 1);
    __syncthreads();
    int w = (t < nodes) ? deg[t] + 1 : 0;
    s[t] = w;
    __syncthreads();
    for (int o = 1; o < 256; o <<= 1) {
        int x = (t >= o) ? s[t - o] : 0;
        __syncthreads();
        s[t] += x;
        __syncthreads();
    }
    int ex = s[t] - w;
    cur[t] = ex;
    if (t < nodes) {
        rp[n0 + t] = base + ex;
        dinv[n0 + t] = rsqrtf((float)(deg[t] + 1));
    }
    __syncthreads();
    for (int i = t; i < cnt_b; i += 256) {
        unsigned pk = binned[cbeg + i];
        int d = pk & 255;
        int r = atomicAdd(&cur[d], 1);
        colb[r] = (int)(pk >> 8);
    }
    __syncthreads();
    if (t < nodes) colb[cur[t]] = n0 + t;
    __syncthreads();
    int tot = cnt_b + nodes;
    for (int i = t; i < tot; i += 256) col[base + i] = colb[i];
    if (b == 0 && t == 0) rp[NN] = NE + NN;
}

// ---------------- fused prep: graph bounds + Wt transpose-cvt + x pad/scale ----------------

__global__ void k_prep(const float* __restrict__ w12, half_t* __restrict__ Wt,
                       const float* __restrict__ x, const float* __restrict__ dinv,
                       half_t* __restrict__ xh, const int* __restrict__ batch,
                       int* __restrict__ gstart) {
    int b = blockIdx.x;
    if (b < 16) {            // gbound: 16*256 = 4096 graphs
        int g = b * 256 + threadIdx.x;
        int lo = 0, hi = NN;
        while (lo < hi) { int m = (lo + hi) >> 1; if (batch[m] < g) lo = m + 1; else hi = m; }
        gstart[g] = lo;
        if (g == 0) gstart[NG] = NN;
    } else if (b < 144) {    // cvtw: 128 blocks x 256 = 32768
        int i = (b - 16) * 256 + threadIdx.x;
        int m = i >> 14;
        int r = i & 16383;
        int n = r >> 7, k = r & 127;
        Wt[i] = (half_t)w12[m * 16384 + k * 128 + n];
    } else {                 // padx
        int n = (b - 144) * 256 + threadIdx.x;
        if (n >= NN) return;
        float dv = dinv[n];
        half_t buf[16];
#pragma unroll
        for (int k = 0; k < 9; ++k) buf[k] = (half_t)(x[n * 9 + k] * dv);
#pragma unroll
        for (int k = 9; k < 16; ++k) buf[k] = (half_t)0.f;
        *(half8*)&xh[n * 16] = *(half8*)buf;
        *(half8*)&xh[n * 16 + 8] = *(half8*)(buf + 8);
    }
}

// ---------------- fused layer 0: agg(x) in LDS, then @ w0 -> gf + stats ----------------

__global__ __launch_bounds__(256) void k_l0(const half_t* __restrict__ xh,
        const float* __restrict__ dinv, const float* __restrict__ w0,
        const int* __restrict__ rp, const int* __restrict__ col,
        half_t* __restrict__ gout, float* __restrict__ ps, float* __restrict__ ps2) {
    __shared__ float ax[64][17];
    __shared__ float lsum[4][128], lsq[4][128];
    int t = threadIdx.x;
    int n0 = blockIdx.x * 64;
    // phase 1: gather; 4 lanes per node
    {
        int ln = t >> 2, sub = (t & 3) * 4;
        int n = n0 + ln;
        float acc[4] = {0.f, 0.f, 0.f, 0.f};
        if (n < NN) {
            int s = rp[n], e = rp[n + 1];
            int i = s;
            for (; i + 1 < e; i += 2) {
                half4v v0 = *(const half4v*)&xh[col[i] * 16 + sub];
                half4v v1 = *(const half4v*)&xh[col[i + 1] * 16 + sub];
#pragma unroll
                for (int j = 0; j < 4; ++j) acc[j] += (float)v0[j] + (float)v1[j];
            }
            if (i < e) {
                half4v v0 = *(const half4v*)&xh[col[i] * 16 + sub];
#pragma unroll
                for (int j = 0; j < 4; ++j) acc[j] += (float)v0[j];
            }
            float dv = dinv[n];
#pragma unroll
            for (int j = 0; j < 4; ++j) ax[ln][sub + j] = acc[j] * dv;
        } else {
#pragma unroll
            for (int j = 0; j < 4; ++j) ax[ln][sub + j] = 0.f;
        }
    }
    __syncthreads();
    // phase 2: mm9 from LDS; wave w -> nodes n0+w*16 .. +15
    int w = t >> 6, l = t & 63, c = 2 * l;
    float2 wv[9];
#pragma unroll
    for (int k = 0; k < 9; ++k) wv[k] = *(const float2*)&w0[k * HD + c];
    float s0 = 0.f, s1 = 0.f, q0 = 0.f, q1 = 0.f;
    for (int j = 0; j < 16; ++j) {
        int ln2 = w * 16 + j;
        int n = n0 + ln2;
        if (n >= NN) break;
        float2 acc = make_float2(0.f, 0.f);
#pragma unroll
        for (int k = 0; k < 9; ++k) {
            float a = ax[ln2][k];
            acc.x += a * wv[k].x;
            acc.y += a * wv[k].y;
        }
        half_t hx = (half_t)acc.x, hy = (half_t)acc.y;
        half2v hv = {hx, hy};
        *(half2v*)&gout[n * HD + c] = hv;
        float fx = (float)hx, fy = (float)hy;
        s0 += fx; q0 += fx * fx; s1 += fy; q1 += fy * fy;
    }
    lsum[w][c] = s0; lsum[w][c + 1] = s1;
    lsq[w][c] = q0;  lsq[w][c + 1] = q1;
    __syncthreads();
    if (t < 128) {
        ps[blockIdx.x * 128 + t] = lsum[0][t] + lsum[1][t] + lsum[2][t] + lsum[3][t];
        ps2[blockIdx.x * 128 + t] = lsq[0][t] + lsq[1][t] + lsq[2][t] + lsq[3][t];
    }
}

// one block per channel, tree-reduce nb partials
__global__ __launch_bounds__(256) void k_stats2(const float* __restrict__ ps,
        const float* __restrict__ ps2, const float* __restrict__ g,
        const float* __restrict__ be, float* __restrict__ scale,
        float* __restrict__ shift, int nb) {
    __shared__ float sa[256], sb[256];
    int c = blockIdx.x, t = threadIdx.x;
    float S = 0.f, Q = 0.f;
    for (int i = t; i < nb; i += 256) {
        S += ps[i * 128 + c];
        Q += ps2[i * 128 + c];
    }
    sa[t] = S; sb[t] = Q;
    __syncthreads();
    for (int o = 128; o; o >>= 1) {
        if (t < o) { sa[t] += sa[t + o]; sb[t] += sb[t + o]; }
        __syncthreads();
    }
    if (t == 0) {
        double mu = (double)sa[0] / NN;
        double var = (double)sb[0] / NN - mu * mu;
        float sc = g[c] * rsqrtf((float)var + EPSV);
        scale[c] = sc;
        shift[c] = be[c] - (float)mu * sc;
    }
}

// ---------------- MFMA matmul: hh = relu(bn(gf)) @ W · dinv, fp16 out ----------------

__global__ __launch_bounds__(256) void k_mm_mfma(const half_t* __restrict__ gf,
        const float* __restrict__ scale, const float* __restrict__ shift,
        const float* __restrict__ dinv, const half_t* __restrict__ Wt,
        half_t* __restrict__ hh) {
    __shared__ half_t wlds[16384];   // [n][k] fp16, 16B-XOR swizzled
    int t = threadIdx.x;
#pragma unroll
    for (int j = 0; j < 8; ++j) {
        int cidx = t * 8 + j;          // 16-B chunk
        int n = cidx >> 4, k8 = cidx & 15;
        half8 v = *(const half8*)&Wt[cidx * 8];
        int byte = n * 256 + ((k8 * 16) ^ ((n & 7) << 4));
        *(half8*)((char*)wlds + byte) = v;
    }
    __syncthreads();
    int w = t >> 6, l = t & 63;
    int lr = l & 15, lg = l >> 4;
    int base = (blockIdx.x * 4 + w) * 16;
    int row = base + lr;
    bool rowok = row < NN;
    f32x4 acc[8];
#pragma unroll
    for (int nt = 0; nt < 8; ++nt) acc[nt] = (f32x4){0.f, 0.f, 0.f, 0.f};
#pragma unroll
    for (int kk = 0; kk < 4; ++kk) {
        int ch0 = kk * 32 + lg * 8;
        half8 a8;
        if (rowok) {
            half8 hv = *(const half8*)&gf[row * HD + ch0];
            f32x4 sc0 = *(const f32x4*)&scale[ch0];
            f32x4 sc1 = *(const f32x4*)&scale[ch0 + 4];
            f32x4 sh0 = *(const f32x4*)&shift[ch0];
            f32x4 sh1 = *(const f32x4*)&shift[ch0 + 4];
#pragma unroll
            for (int i = 0; i < 4; ++i)
                a8[i] = (half_t)fmaxf((float)hv[i] * sc0[i] + sh0[i], 0.f);
#pragma unroll
            for (int i = 0; i < 4; ++i)
                a8[4 + i] = (half_t)fmaxf((float)hv[4 + i] * sc1[i] + sh1[i], 0.f);
        } else {
#pragma unroll
            for (int i = 0; i < 8; ++i) a8[i] = (half_t)0.f;
        }
        int kbyte = kk * 64 + lg * 16;
#pragma unroll
        for (int nt = 0; nt < 8; ++nt) {
            int n = nt * 16 + lr;
            half8 b8 = *(const half8*)((const char*)wlds + n * 256 + (kbyte ^ ((n & 7) << 4)));
            acc[nt] = __builtin_amdgcn_mfma_f32_16x16x32_f16(a8, b8, acc[nt], 0, 0, 0);
        }
    }
#pragma unroll
    for (int i = 0; i < 4; ++i) {
        int r = base + lg * 4 + i;
        if (r < NN) {
            float dv = dinv[r];
#pragma unroll
            for (int nt = 0; nt < 8; ++nt)
                hh[r * HD + nt * 16 + lr] = (half_t)(acc[nt][i] * dv);
        }
    }
}

// ---------------- fp16 CSR gather (round-5 exact) + fused stats ----------------

__global__ __launch_bounds__(256) void k_agg_h(const half_t* __restrict__ hh,
        const float* __restrict__ dinv, half_t* __restrict__ gout,
        const int* __restrict__ rp, const int* __restrict__ col,
        float* __restrict__ ps, float* __restrict__ ps2) {
    __shared__ float lsum[16][128], lsq[16][128];
    int t = threadIdx.x, w = t >> 6, l = t & 63;
    int sub = l >> 4, li = l & 15;
    int sg = w * 4 + sub;             // 0..15
    int c0 = li * 8;
    int n0 = blockIdx.x * CH_AG;
    int n1 = min(NN, n0 + CH_AG);
    float sacc[8], qacc[8];
#pragma unroll
    for (int j = 0; j < 8; ++j) { sacc[j] = 0.f; qacc[j] = 0.f; }
    for (int n = n0 + sg; n < n1; n += 16) {
        int s = rp[n], e = rp[n + 1];
        float facc[8];
#pragma unroll
        for (int j = 0; j < 8; ++j) facc[j] = 0.f;
        int i = s;
        for (; i + 1 < e; i += 2) {
            int ca = col[i], cb = col[i + 1];
            half8 v0 = *(const half8*)&hh[ca * HD + c0];
            half8 v1 = *(const half8*)&hh[cb * HD + c0];
#pragma unroll
            for (int j = 0; j < 8; ++j) facc[j] += (float)v0[j] + (float)v1[j];
        }
        if (i < e) {
            half8 v0 = *(const half8*)&hh[col[i] * HD + c0];
#pragma unroll
            for (int j = 0; j < 8; ++j) facc[j] += (float)v0[j];
        }
        float dv = dinv[n];
        half8 hv;
#pragma unroll
        for (int j = 0; j < 8; ++j) hv[j] = (half_t)(facc[j] * dv);
        *(half8*)&gout[n * HD + c0] = hv;
#pragma unroll
        for (int j = 0; j < 8; ++j) {
            float f = (float)hv[j];
            sacc[j] += f;
            qacc[j] += f * f;
        }
    }
#pragma unroll
    for (int j = 0; j < 8; ++j) {
        lsum[sg][c0 + j] = sacc[j];
        lsq[sg][c0 + j] = qacc[j];
    }
    __syncthreads();
    if (t < 128) {
        float S = 0.f, Q = 0.f;
#pragma unroll
        for (int g = 0; g < 16; ++g) { S += lsum[g][t]; Q += lsq[g][t]; }
        ps[blockIdx.x * 128 + t] = S;
        ps2[blockIdx.x * 128 + t] = Q;
    }
}

// ---------------- pooling (2 waves/graph) + MLP ----------------

__global__ __launch_bounds__(256) void k_pool(const half_t* __restrict__ h,
        const float* __restrict__ scale, const float* __restrict__ shift,
        const int* __restrict__ gstart, float* __restrict__ xg) {
    __shared__ float ssum[2][2][128], smax[2][2][128];
    int t = threadIdx.x, w = t >> 6, l = t & 63;
    int gi = w >> 1, half = w & 1;
    int g = blockIdx.x * 2 + gi;
    int c = 2 * l;
    float2 sc = make_float2(scale[c], scale[c + 1]);
    float2 sh = make_float2(shift[c], shift[c + 1]);
    int s = gstart[g], e = gstart[g + 1];
    int mid = (s + e) >> 1;
    int rs = half ? mid : s;
    int re = half ? e : mid;
    float2 sum = make_float2(0.f, 0.f), mx = make_float2(-3e38f, -3e38f);
    for (int r = rs; r < re; ++r) {
        half2v hv = *(const half2v*)&h[r * HD + c];
        float vx = fmaxf((float)hv[0] * sc.x + sh.x, 0.f);
        float vy = fmaxf((float)hv[1] * sc.y + sh.y, 0.f);
        sum.x += vx; sum.y += vy;
        mx.x = fmaxf(mx.x, vx); mx.y = fmaxf(mx.y, vy);
    }
    ssum[gi][half][c] = sum.x; ssum[gi][half][c + 1] = sum.y;
    smax[gi][half][c] = mx.x;  smax[gi][half][c + 1] = mx.y;
    __syncthreads();
    if (half == 0) {
        float2 stot = make_float2(ssum[gi][0][c] + ssum[gi][1][c],
                                  ssum[gi][0][c + 1] + ssum[gi][1][c + 1]);
        float2 mtot = make_float2(fmaxf(smax[gi][0][c], smax[gi][1][c]),
                                  fmaxf(smax[gi][0][c + 1], smax[gi][1][c + 1]));
        float2 mean = make_float2(0.f, 0.f), mxo = make_float2(0.f, 0.f);
        if (e > s) {
            float cnt = (float)(e - s);
            mean.x = stot.x / cnt; mean.y = stot.y / cnt;
            mxo = mtot;
        }
        *(float2*)&xg[g * 256 + c] = mean;
        *(float2*)&xg[g * 256 + 128 + c] = mxo;
    }
}

#define GPB 8
__global__ __launch_bounds__(256) void k_mlp(const float* __restrict__ xg,
                                             const float* __restrict__ m0w, const float* __restrict__ m0b,
                                             const float* __restrict__ m1w, const float* __restrict__ m1b,
                                             const float* __restrict__ m2w, const float* __restrict__ m2b,
                                             float* __restrict__ out) {
    __shared__ float xs[GPB][256];
    __shared__ float h1[GPB][256];
    __shared__ float h2[GPB][64];
    int t = threadIdx.x;
    int g0 = blockIdx.x * GPB;
#pragma unroll
    for (int j = 0; j < GPB; ++j) xs[j][t] = xg[(g0 + j) * 256 + t];
    __syncthreads();
    float acc[GPB];
#pragma unroll
    for (int j = 0; j < GPB; ++j) acc[j] = m0b[t];
    for (int i = 0; i < 256; ++i) {
        float wv = m0w[i * 256 + t];
#pragma unroll
        for (int j = 0; j < GPB; ++j) acc[j] += xs[j][i] * wv;
    }
#pragma unroll
    for (int j = 0; j < GPB; ++j) h1[j][t] = fmaxf(acc[j], 0.f);
    __syncthreads();
    if (t < 64) {
        float a2[GPB];
#pragma unroll
        for (int j = 0; j < GPB; ++j) a2[j] = m1b[t];
        for (int i = 0; i < 256; ++i) {
            float wv = m1w[i * 64 + t];
#pragma unroll
            for (int j = 0; j < GPB; ++j) a2[j] += h1[j][i] * wv;
        }
#pragma unroll
        for (int j = 0; j < GPB; ++j) h2[j][t] = fmaxf(a2[j], 0.f);
    }
    __syncthreads();
    if (t < 64) {
#pragma unroll
        for (int j = 0; j < GPB; ++j) {
            float v = h2[j][t] * m2w[t];
            for (int off = 32; off; off >>= 1) v += __shfl_down(v, off);
            if (t == 0) out[g0 + j] = v + m2b[0];
        }
    }
}

// ---------------- launch ----------------

extern "C" void kernel_launch(void* const* d_in, const int* in_sizes, int n_in,
                              void* d_out, int out_size, void* d_ws, size_t ws_size,
                              hipStream_t stream) {
    const float* x    = (const float*)d_in[0];
    const int*   ei   = (const int*)d_in[1];
    const int*   batch= (const int*)d_in[2];
    const float* w0   = (const float*)d_in[3];
    const float* w12  = (const float*)d_in[4];
    // d_in[5] = cb : cancelled by BN mean-subtraction
    const float* bn_g = (const float*)d_in[6];
    const float* bn_b = (const float*)d_in[7];
    const float* m0w  = (const float*)d_in[8];
    const float* m0b  = (const float*)d_in[9];
    const float* m1w  = (const float*)d_in[10];
    const float* m1b  = (const float*)d_in[11];
    const float* m2w  = (const float*)d_in[12];
    const float* m2b  = (const float*)d_in[13];
    float* out = (float*)d_out;

    char* p = (char*)d_ws;
    auto alloc = [&](size_t bytes) {
        void* r = (void*)p;
        p += (bytes + 255) & ~(size_t)255;
        return r;
    };
    half_t*   gf0    = (half_t*)alloc((size_t)NN * HD * 2);
    half_t*   gf1    = (half_t*)alloc((size_t)NN * HD * 2);
    half_t*   hh     = (half_t*)alloc((size_t)NN * HD * 2);
    half_t*   xh     = (half_t*)alloc((size_t)NN * 16 * 2);
    half_t*   Wt     = (half_t*)alloc((size_t)2 * 128 * 128 * 2);
    float*    dinv   = (float*)alloc((size_t)NN * 4);
    int*      rp     = (int*)alloc((size_t)(NN + 1) * 4);
    int*      col    = (int*)alloc((size_t)(NE + NN) * 4);
    unsigned* binned = (unsigned*)alloc((size_t)NE * 4);
    int*      bcnt   = (int*)alloc(512 * 4);
    int*      ebase  = (int*)alloc(512 * 4);
    int*      gcur   = (int*)alloc(512 * 4);
    int*      gstart = (int*)alloc((size_t)(NG + 1) * 4);
    float*    ps     = (float*)alloc((size_t)NB_AG * 128 * 4);
    float*    ps2    = (float*)alloc((size_t)NB_AG * 128 * 4);
    float*    scb    = (float*)alloc(3 * 128 * 4);
    float*    shb    = (float*)alloc(3 * 128 * 4);
    float*    xg     = (float*)alloc((size_t)NG * 256 * 4);

    // ---- CSR build ----
    k_zero_i32<<<2, 256, 0, stream>>>(bcnt, 512);
    k_bcount<<<NBIN_BLK, 256, 0, stream>>>(ei, bcnt);
    k_bscan<<<1, 512, 0, stream>>>(bcnt, ebase, gcur);
    k_bin<<<NBIN_BLK, 256, 0, stream>>>(ei, gcur, binned);
    k_csr<<<NBUCK, 256, 0, stream>>>(binned, ebase, rp, dinv, col);

    // ---- prep (gbound + Wt cvt + x pad) ----
    k_prep<<<144 + (NN + 255) / 256, 256, 0, stream>>>(w12, Wt, x, dinv, xh, batch, gstart);

    // ---- layer 0 (fused agg + mm9 + stats) ----
    k_l0<<<NB_L0, 256, 0, stream>>>(xh, dinv, w0, rp, col, gf0, ps, ps2);
    k_stats2<<<128, 256, 0, stream>>>(ps, ps2, bn_g + 0, bn_b + 0, scb + 0, shb + 0, NB_L0);

    // ---- layer 1 ----
    k_mm_mfma<<<(NN + 63) / 64, 256, 0, stream>>>(gf0, scb + 0, shb + 0, dinv, Wt, hh);
    k_agg_h<<<NB_AG, 256, 0, stream>>>(hh, dinv, gf1, rp, col, ps, ps2);
    k_stats2<<<128, 256, 0, stream>>>(ps, ps2, bn_g + 128, bn_b + 128, scb + 128, shb + 128, NB_AG);

    // ---- layer 2 ----
    k_mm_mfma<<<(NN + 63) / 64, 256, 0, stream>>>(gf1, scb + 128, shb + 128, dinv, Wt + 16384, hh);
    k_agg_h<<<NB_AG, 256, 0, stream>>>(hh, dinv, gf0, rp, col, ps, ps2);
    k_stats2<<<128, 256, 0, stream>>>(ps, ps2, bn_g + 256, bn_b + 256, scb + 256, shb + 256, NB_AG);

    // ---- pool + MLP ----
    k_pool<<<NG / 2, 256, 0, stream>>>(gf0, scb + 256, shb + 256, gstart, xg);
    k_mlp<<<NG / GPB, 256, 0, stream>>>(xg, m0w, m0b, m1w, m1b, m2w, m2b, out);
}